// Round 10
// baseline (994.704 us; speedup 1.0000x reference)
//
#include <hip/hip_runtime.h>
#include <hip/hip_bf16.h>
#include <math.h>

#define BB 4096
#define TT 5
#define KK 4
#define NLANES 12
#define GH 64
#define GO 32
#define GAT_TOT 256
#define SAGE_H 64
#define GRU_H 32

typedef __attribute__((ext_vector_type(8))) short short8v;
typedef __attribute__((ext_vector_type(8))) unsigned short ushort8v;
typedef __attribute__((ext_vector_type(4))) unsigned short ushort4v;
typedef __attribute__((ext_vector_type(4))) float f32x4;

__device__ __forceinline__ unsigned short f2bf(float x) {
    __hip_bfloat16 h = __float2bfloat16(x);
    return __builtin_bit_cast(unsigned short, h);
}
__device__ __forceinline__ float bf2f(unsigned short b) {
    return __uint_as_float(((unsigned)b) << 16);
}

// ---------------------------------------------------------------------------
// Setup: wt bf16 [256][64] (W^T), statc[20] LN quadratic-form coefficients,
// and transposed GRU/MLP weights for kernel B (contiguous float4 rows).
// ---------------------------------------------------------------------------
__global__ void setup_kernel(const float* __restrict__ coopW,
                             const float* __restrict__ confW,
                             const float* __restrict__ projW,
                             const float* __restrict__ projB,
                             const float* __restrict__ gfWx, const float* __restrict__ gbWx,
                             const float* __restrict__ pW1, const float* __restrict__ vW1,
                             const float* __restrict__ pW2, const float* __restrict__ vW2,
                             const float* __restrict__ pWo,
                             unsigned short* __restrict__ wt,
                             float* __restrict__ statc,
                             float* __restrict__ gfWxT, float* __restrict__ gbWxT,
                             float* __restrict__ pW1T, float* __restrict__ vW1T,
                             float* __restrict__ pW2T, float* __restrict__ vW2T,
                             float* __restrict__ pWoT) {
    const int tnum = threadIdx.x;   // 256 threads
    {
        int c = tnum;
        int g = c >> 7, hh = (c >> 5) & 3, o = c & 31;
        const float* W = (g ? confW : coopW) + hh * (GH * GO) + o;
        for (int k = 0; k < GH; ++k)
            wt[c * GH + k] = f2bf(W[k * GO]);
    }
    // transposes for kernel B
    for (int i = tnum; i < 96 * 64; i += 256) {
        int j = i >> 6, f = i & 63;
        gfWxT[i] = gfWx[f * 96 + j];
        gbWxT[i] = gbWx[f * 96 + j];
    }
    for (int i = tnum; i < 128 * 320; i += 256) {
        int j = i / 320, c = i - j * 320;
        pW1T[i] = pW1[c * 128 + j];
        vW1T[i] = vW1[c * 128 + j];
    }
    for (int i = tnum; i < 64 * 128; i += 256) {
        int j = i >> 7, c = i & 127;
        pW2T[i] = pW2[c * 64 + j];
        vW2T[i] = vW2[c * 64 + j];
    }
    for (int i = tnum; i < 8 * 64; i += 256) {
        int j = i >> 6, c = i & 63;
        pWoT[i] = pWo[c * 8 + j];
    }
    if (tnum == 0) {
        float Wm[4], bm = 0.f;
        for (int c = 0; c < 4; ++c) {
            float s = 0.f;
            for (int f = 0; f < GH; ++f) s += projW[c * GH + f];
            Wm[c] = s * (1.f / GH);
        }
        for (int f = 0; f < GH; ++f) bm += projB[f];
        bm *= (1.f / GH);
        int idx = 0;
        for (int c = 0; c < 4; ++c)
            for (int d = c; d < 4; ++d) {
                float s = 0.f;
                for (int f = 0; f < GH; ++f)
                    s += (projW[c * GH + f] - Wm[c]) * (projW[d * GH + f] - Wm[d]);
                statc[idx++] = s * (1.f / GH) * (c == d ? 1.f : 2.f);
            }
        for (int c = 0; c < 4; ++c) {
            float s = 0.f;
            for (int f = 0; f < GH; ++f)
                s += (projW[c * GH + f] - Wm[c]) * (projB[f] - bm);
            statc[10 + c] = s * (2.f / GH);
        }
        {
            float s = 0.f;
            for (int f = 0; f < GH; ++f)
                s += (projB[f] - bm) * (projB[f] - bm);
            statc[14] = s * (1.f / GH);
        }
        for (int c = 0; c < 4; ++c) statc[15 + c] = Wm[c];
        statc[19] = bm;
    }
}

// ---------------------------------------------------------------------------
// Kernel A: r9 structure, LDS packed to exactly 40 KB (4 blocks/CU) with a
// mid-GEMM barrier enabling the s_sd<->s_hb alias; launch_bounds(256,4);
// single-pass softmax.
// ---------------------------------------------------------------------------
__global__ __launch_bounds__(256, 4) void gat_sage_kernel(
    const float* __restrict__ selfF, const float* __restrict__ nbF,
    const float* __restrict__ mask,
    const float* __restrict__ projW, const float* __restrict__ projB,
    const float* __restrict__ projG, const float* __restrict__ projBt,
    const float* __restrict__ coopSrc, const float* __restrict__ coopDst,
    const float* __restrict__ confSrc, const float* __restrict__ confDst,
    const unsigned short* __restrict__ wt, const float* __restrict__ statc,
    const float* __restrict__ sageW, const float* __restrict__ sageB,
    float* __restrict__ hsage, float* __restrict__ embLast)
{
    // 40960 B total. Region A (0..32767): s_x/s_stat (P0-P1) -> WhT (P2-P4)
    // -> s_att (P5-P6) -> s_in/s_part (P7). Region B (32768..40959):
    // s_hb (P1-P2 A-frags) -> s_sd (late P2..P5, after mid-GEMM barrier).
    __shared__ __align__(16) char s_all[40960];

    float* s_x = (float*)s_all;                                          // 960 B
    float2* s_stat = (float2*)(s_all + 1024);                            // 512 B
    unsigned short* WhT = (unsigned short*)s_all;                        // 32 KB
    float (*s_att)[8][NLANES][16] = (float (*)[8][NLANES][16])s_all;     // 30720 B
    float* s_in = (float*)s_all;                                         // 2 KB
    float (*s_part)[SAGE_H] = (float (*)[SAGE_H])(s_all + 2048);         // 1 KB
    unsigned short* s_hb = (unsigned short*)(s_all + 32768);             // 8 KB
    float (*s_sd)[8][64] = (float (*)[8][64])(s_all + 32768);            // 4 KB

    const int bid = blockIdx.x;          // b*T + t
    const int b = bid / TT, t = bid % TT;
    const int tid = threadIdx.x;

    const int gh = tid >> 5;                   // pool: col = tid
    const int wv = tid >> 6, f = tid & 63;     // wave, lane
    const int l15 = f & 15, g4 = f >> 4;

    // ---- P0: stage inputs + per-row LN stats (covariance trick) ----
    if (tid < 60) {
        int inst = tid / 12, j = tid % 12;
        const float* xp = (inst == 0)
            ? (selfF + (size_t)bid * 48)
            : (nbF + (size_t)((b * KK + (inst - 1)) * TT + t) * 48);
        float4 xv = ((const float4*)xp)[j];
        ((float4*)s_x)[tid] = xv;
        const float* sc = statc;
        float mean = xv.x * sc[15] + xv.y * sc[16] + xv.z * sc[17] + xv.w * sc[18] + sc[19];
        float var = sc[0] * xv.x * xv.x + sc[1] * xv.x * xv.y + sc[2] * xv.x * xv.z
                  + sc[3] * xv.x * xv.w + sc[4] * xv.y * xv.y + sc[5] * xv.y * xv.z
                  + sc[6] * xv.y * xv.w + sc[7] * xv.z * xv.z + sc[8] * xv.z * xv.w
                  + sc[9] * xv.w * xv.w
                  + sc[10] * xv.x + sc[11] * xv.y + sc[12] * xv.z + sc[13] * xv.w + sc[14];
        s_stat[tid] = make_float2(mean, rsqrtf(fmaxf(var, 0.f) + 1e-5f));
    }

    // proj row in registers (lane = feature f)
    const float pw0 = projW[0 * GH + f], pw1 = projW[1 * GH + f];
    const float pw2 = projW[2 * GH + f], pw3 = projW[3 * GH + f];
    const float pb = projB[f], pg = projG[f], pbt = projBt[f];
    __syncthreads();

    // ---- P1: proj + LN + relu -> s_hb (bf16, frag-swizzled); rows 60..63 zero
    #pragma unroll
    for (int i = 0; i < 15; ++i) {
        const int r = wv + i * 4;
        float2 st = s_stat[r];
        float h = fmaf(s_x[r * 4 + 0], pw0, fmaf(s_x[r * 4 + 1], pw1,
                  fmaf(s_x[r * 4 + 2], pw2, fmaf(s_x[r * 4 + 3], pw3, pb))));
        float nv = (h - st.x) * (st.y * pg) + pbt;
        nv = fmaxf(nv, 0.f);
        s_hb[r * 64 + (((f >> 3) ^ (r & 7)) << 3) + (f & 7)] = f2bf(nv);
    }
    {   // zero rows 60..63 (wave wv -> row 60+wv)
        const int r = 60 + wv;
        s_hb[r * 64 + (((f >> 3) ^ (r & 7)) << 3) + (f & 7)] = 0;
    }
    __syncthreads();

    // ---- P2: GEMM Wh = h[64x64] @ W[64x256]; reduce + pack from C-frags ----
    {
        f32x4 c[4][4];
        #pragma unroll
        for (int mt = 0; mt < 4; ++mt)
            #pragma unroll
            for (int nt = 0; nt < 4; ++nt)
                c[mt][nt] = (f32x4){0.f, 0.f, 0.f, 0.f};

        #pragma unroll
        for (int kt = 0; kt < 2; ++kt) {
            const int kc = kt * 4 + g4;
            short8v a[4], bfr[4];
            #pragma unroll
            for (int mt = 0; mt < 4; ++mt) {
                const int r = mt * 16 + l15;
                a[mt] = *(const short8v*)&s_hb[r * 64 + ((kc ^ (r & 7)) << 3)];
            }
            #pragma unroll
            for (int nt = 0; nt < 4; ++nt)
                bfr[nt] = *(const short8v*)&wt[(wv * 64 + nt * 16 + l15) * GH + kc * 8];
            #pragma unroll
            for (int mt = 0; mt < 4; ++mt)
                #pragma unroll
                for (int nt = 0; nt < 4; ++nt)
                    c[mt][nt] = __builtin_amdgcn_mfma_f32_16x16x32_bf16(
                        a[mt], bfr[nt], c[mt][nt], 0, 0, 0);
        }

        // all s_hb reads done across the block -> safe to alias s_sd onto it
        __syncthreads();

        // attention scalars from C-frags: 16-lane shuffle reduce over l15
        {
            float asv[4], adv[4];
            #pragma unroll
            for (int nt = 0; nt < 4; ++nt) {
                const int cc = wv * 64 + nt * 16 + l15;
                const int g = cc >> 7, hh = (cc >> 5) & 3, oo = cc & 31;
                asv[nt] = (g ? confSrc : coopSrc)[hh * GO + oo];
                adv[nt] = (g ? confDst : coopDst)[hh * GO + oo];
            }
            #pragma unroll
            for (int p = 0; p < 2; ++p) {
                const int ghw = 2 * wv + p;
                #pragma unroll
                for (int mt = 0; mt < 4; ++mt) {
                    float sv[4], dv[4];
                    #pragma unroll
                    for (int r = 0; r < 4; ++r) {
                        sv[r] = c[mt][2 * p][r] * asv[2 * p] + c[mt][2 * p + 1][r] * asv[2 * p + 1];
                        dv[r] = c[mt][2 * p][r] * adv[2 * p] + c[mt][2 * p + 1][r] * adv[2 * p + 1];
                    }
                    #pragma unroll
                    for (int m = 1; m < 16; m <<= 1) {
                        #pragma unroll
                        for (int r = 0; r < 4; ++r) {
                            sv[r] += __shfl_xor(sv[r], m);
                            dv[r] += __shfl_xor(dv[r], m);
                        }
                    }
                    if (l15 == 0) {
                        const int rb = mt * 16 + g4 * 4;
                        *(float4*)&s_sd[0][ghw][rb] = make_float4(sv[0], sv[1], sv[2], sv[3]);
                        *(float4*)&s_sd[1][ghw][rb] = make_float4(dv[0], dv[1], dv[2], dv[3]);
                    }
                }
            }
        }

        // pack C frags -> WhT bf16 [col][64 rows], swizzled rows
        #pragma unroll
        for (int mt = 0; mt < 4; ++mt) {
            #pragma unroll
            for (int nt = 0; nt < 4; ++nt) {
                const int cc = wv * 64 + nt * 16 + l15;
                const int rb = mt * 16 + g4 * 4;
                ushort4v p;
                p.x = f2bf(c[mt][nt][0]); p.y = f2bf(c[mt][nt][1]);
                p.z = f2bf(c[mt][nt][2]); p.w = f2bf(c[mt][nt][3]);
                const int idx = cc * 64 + (((rb >> 3) ^ (cc & 7)) << 3) + (rb & 7);
                *(ushort4v*)&WhT[idx] = p;
            }
        }
    }
    __syncthreads();

    // ---- P4: readback acc[r] = Wh[r][col=tid] ----
    float acc[60];
    {
        const int cs = tid & 7;
        #pragma unroll
        for (int ch = 0; ch < 8; ++ch) {
            ushort8v v = *(const ushort8v*)&WhT[tid * 64 + ((ch ^ cs) << 3)];
            #pragma unroll
            for (int j = 0; j < 8; ++j) {
                const int r = ch * 8 + j;
                if (r < 60) acc[r] = bf2f(v[j]);
            }
        }
    }
    __syncthreads();   // WhT dead; s_att region live from here

    // ---- P5: parallel masked softmax, single ev pass, swizzled writes ----
    #pragma unroll
    for (int round = 0; round < 2; ++round) {
        const int task = tid + round * 256;
        if (task < 480) {
            const int inst = task / 96;
            const int rem = task - inst * 96;
            const int gh2 = rem / 12, n2 = rem - (rem / 12) * 12;
            const int g2 = gh2 >> 2;
            const int an = n2 / 3;
            const float sn = s_sd[0][gh2][inst * 12 + n2];
            float vq[12];
            float mx = -1e30f;
            #pragma unroll
            for (int mm = 0; mm < NLANES; ++mm) {
                int am = mm / 3;
                bool valid = (g2 == 0) ? (am == an) : (am != an || mm == n2);
                float ev = sn + s_sd[1][gh2][inst * 12 + mm];
                ev = ev > 0.f ? ev : 0.2f * ev;
                vq[mm] = valid ? ev : -1e30f;
                mx = fmaxf(mx, vq[mm]);
            }
            float sum = 0.f;
            #pragma unroll
            for (int mm = 0; mm < NLANES; ++mm) {
                float ex = __expf(vq[mm] - mx);
                vq[mm] = ex; sum += ex;
            }
            const float inv = 1.f / sum;
            const int sw = n2 & 3;
            float4* arow = (float4*)s_att[inst][gh2][n2];
            arow[0 ^ sw] = make_float4(vq[0] * inv, vq[1] * inv, vq[2] * inv, vq[3] * inv);
            arow[1 ^ sw] = make_float4(vq[4] * inv, vq[5] * inv, vq[6] * inv, vq[7] * inv);
            arow[2 ^ sw] = make_float4(vq[8] * inv, vq[9] * inv, vq[10] * inv, vq[11] * inv);
        }
    }
    __syncthreads();

    // ---- P6: pool (swizzled float4 att reads) + agg + concat ----
    {
        float pooled_arr[5];
        #pragma unroll
        for (int inst = 0; inst < 5; ++inst) {
            float pooled = 0.f;
            #pragma unroll
            for (int n = 0; n < NLANES; ++n) {
                const int sw = n & 3;
                const float4* arow = (const float4*)s_att[inst][gh][n];
                float4 a0 = arow[0 ^ sw], a1 = arow[1 ^ sw], a2 = arow[2 ^ sw];
                float v = a0.x * acc[inst * 12 + 0] + a0.y * acc[inst * 12 + 1]
                        + a0.z * acc[inst * 12 + 2] + a0.w * acc[inst * 12 + 3]
                        + a1.x * acc[inst * 12 + 4] + a1.y * acc[inst * 12 + 5]
                        + a1.z * acc[inst * 12 + 6] + a1.w * acc[inst * 12 + 7]
                        + a2.x * acc[inst * 12 + 8] + a2.y * acc[inst * 12 + 9]
                        + a2.z * acc[inst * 12 + 10] + a2.w * acc[inst * 12 + 11];
                v = v > 0.f ? v : (__expf(v) - 1.f);
                pooled += v;
            }
            pooled_arr[inst] = pooled * (1.f / 12.f);
        }
        __syncthreads();   // att dead

        const float m0 = mask[b * KK + 0], m1 = mask[b * KK + 1];
        const float m2 = mask[b * KK + 2], m3 = mask[b * KK + 3];
        const float inv = 1.f / fmaxf(m0 + m1 + m2 + m3, 1.f);
        s_in[tid] = pooled_arr[0];
        s_in[GAT_TOT + tid] = (m0 * pooled_arr[1] + m1 * pooled_arr[2]
                             + m2 * pooled_arr[3] + m3 * pooled_arr[4]) * inv;
        if (t == TT - 1) embLast[(size_t)b * GAT_TOT + tid] = pooled_arr[0];
    }
    __syncthreads();

    // ---- P7: central-node GraphSAGE row: split-K over 4 groups ----
    {
        const int j = tid & 63, q = tid >> 6;
        const float4* si4 = (const float4*)s_in;
        float v = 0.f;
        #pragma unroll 8
        for (int cq = q * 32; cq < q * 32 + 32; ++cq) {
            float4 s4 = si4[cq];
            const float* Wp = sageW + (cq * 4) * SAGE_H + j;
            v += s4.x * Wp[0] + s4.y * Wp[SAGE_H] + s4.z * Wp[2 * SAGE_H] + s4.w * Wp[3 * SAGE_H];
        }
        s_part[q][j] = v;
    }
    __syncthreads();
    if (tid < SAGE_H) {
        float v = sageB[tid] + s_part[0][tid] + s_part[1][tid]
                + s_part[2][tid] + s_part[3][tid];
        hsage[(size_t)bid * SAGE_H + tid] = fmaxf(v, 0.f);
    }
}

// ---------------------------------------------------------------------------
// Kernel B: transposed weights (float4 dots), both MLP heads in parallel.
// ---------------------------------------------------------------------------
__global__ __launch_bounds__(256) void gru_head_kernel(
    const float* __restrict__ hsage, const float* __restrict__ embLast,
    const float* __restrict__ gfWxT, const float* __restrict__ gfWh,
    const float* __restrict__ gfbx, const float* __restrict__ gfbh,
    const float* __restrict__ gbWxT, const float* __restrict__ gbWh,
    const float* __restrict__ gbbx, const float* __restrict__ gbbh,
    const float* __restrict__ pW1T, const float* __restrict__ pb1,
    const float* __restrict__ pg1, const float* __restrict__ pbt1,
    const float* __restrict__ pW2T, const float* __restrict__ pb2,
    const float* __restrict__ pg2, const float* __restrict__ pbt2,
    const float* __restrict__ pWoT, const float* __restrict__ pbo,
    const float* __restrict__ vW1T, const float* __restrict__ vb1,
    const float* __restrict__ vg1, const float* __restrict__ vbt1,
    const float* __restrict__ vW2T, const float* __restrict__ vb2,
    const float* __restrict__ vg2, const float* __restrict__ vbt2,
    const float* __restrict__ vWo, const float* __restrict__ vbo,
    float* __restrict__ dout)
{
    __shared__ __align__(16) float s_seq[TT * SAGE_H];
    __shared__ float s_gx[2][TT][96];
    __shared__ float s_hh[2][GRU_H];
    __shared__ __align__(16) float s_joint[320];
    __shared__ __align__(16) float s_h1[2][128];
    __shared__ __align__(16) float s_h2[2][64];
    __shared__ float s_p2[2][2][64];
    __shared__ float s_red[8];

    const int b = blockIdx.x, tid = threadIdx.x;

    if (tid < 80) ((float4*)s_seq)[tid] = ((const float4*)(hsage + (size_t)b * TT * SAGE_H))[tid];
    s_joint[tid] = embLast[(size_t)b * GAT_TOT + tid];
    if (tid < 64) s_hh[tid >> 5][tid & 31] = 0.f;
    __syncthreads();

    // gx precompute (transposed Wx: contiguous float4 rows)
    for (int task = tid; task < 960; task += 256) {
        const int dir = task >= 480;
        const int rem = task - dir * 480;
        const int t5 = rem / 96, j = rem - t5 * 96;
        const float4* w4 = (const float4*)((dir ? gbWxT : gfWxT) + j * 64);
        const float4* x4 = (const float4*)&s_seq[t5 * SAGE_H];
        float v = (dir ? gbbx : gfbx)[j];
        #pragma unroll
        for (int q = 0; q < 16; ++q) {
            float4 xv = x4[q], wvv = w4[q];
            v += xv.x * wvv.x + xv.y * wvv.y + xv.z * wvv.z + xv.w * wvv.w;
        }
        s_gx[dir][t5][j] = v;
    }
    __syncthreads();

    // serial GRU (h-part only)
    for (int s = 0; s < TT; ++s) {
        float hnew = 0.f;
        if (tid < 64) {
            int dir = tid >> 5, j = tid & 31;
            int t5 = dir ? (TT - 1 - s) : s;
            const float* Wh = dir ? gbWh : gfWh;
            const float* bh = dir ? gbbh : gfbh;
            const float* h = s_hh[dir];
            float hr = bh[j], hz = bh[32 + j], hn = bh[64 + j];
            for (int k = 0; k < GRU_H; ++k) {
                float hv = h[k];
                hr += hv * Wh[k * 96 + j];
                hz += hv * Wh[k * 96 + 32 + j];
                hn += hv * Wh[k * 96 + 64 + j];
            }
            float xr = s_gx[dir][t5][j], xz = s_gx[dir][t5][32 + j], xn = s_gx[dir][t5][64 + j];
            float r = 1.f / (1.f + __expf(-(xr + hr)));
            float z = 1.f / (1.f + __expf(-(xz + hz)));
            float nn = tanhf(xn + r * hn);
            hnew = (1.f - z) * nn + z * h[j];
        }
        __syncthreads();
        if (tid < 64) s_hh[tid >> 5][tid & 31] = hnew;
        __syncthreads();
    }
    if (tid < 64) s_joint[GAT_TOT + tid] = s_hh[tid >> 5][tid & 31];
    __syncthreads();

    // ---- MLP layer 1: both heads concurrently; thread = hd*128 + j ----
    const int hd = tid >> 7, j1 = tid & 127;
    float v1;
    {
        const float4* w4 = (const float4*)((hd ? vW1T : pW1T) + j1 * 320);
        const float4* jt = (const float4*)s_joint;
        v1 = (hd ? vb1 : pb1)[j1];
        #pragma unroll 16
        for (int q = 0; q < 80; ++q) {
            float4 a = jt[q], w = w4[q];
            v1 += a.x * w.x + a.y * w.y + a.z * w.z + a.w * w.w;
        }
    }
    {
        float q1 = v1, q2 = v1 * v1;
        #pragma unroll
        for (int m = 1; m < 64; m <<= 1) { q1 += __shfl_xor(q1, m); q2 += __shfl_xor(q2, m); }
        if ((tid & 63) == 0) { s_red[(tid >> 6) * 2] = q1; s_red[(tid >> 6) * 2 + 1] = q2; }
    }
    __syncthreads();
    {
        const int w0 = hd * 2;
        const float sum1 = s_red[w0 * 2] + s_red[w0 * 2 + 2];
        const float sum2 = s_red[w0 * 2 + 1] + s_red[w0 * 2 + 3];
        const float mean = sum1 * (1.f / 128.f);
        const float var = sum2 * (1.f / 128.f) - mean * mean;
        v1 = fmaxf((v1 - mean) * rsqrtf(var + 1e-5f) * (hd ? vg1 : pg1)[j1]
                   + (hd ? vbt1 : pbt1)[j1], 0.f);
        s_h1[hd][j1] = v1;
    }
    __syncthreads();

    // ---- layer 2: thread = hd*128 + q*64 + j, split-K 2 ----
    {
        const int hd2 = tid >> 7, qq = (tid >> 6) & 1, j2 = tid & 63;
        const float4* w4 = (const float4*)((hd2 ? vW2T : pW2T) + j2 * 128 + qq * 64);
        const float4* h4 = (const float4*)&s_h1[hd2][qq * 64];
        float v2 = (qq == 0) ? (hd2 ? vb2 : pb2)[j2] : 0.f;
        #pragma unroll
        for (int q = 0; q < 16; ++q) {
            float4 a = h4[q], w = w4[q];
            v2 += a.x * w.x + a.y * w.y + a.z * w.z + a.w * w.w;
        }
        s_p2[hd2][qq][j2] = v2;
    }
    __syncthreads();
    if (tid < 128) {
        const int hd2 = tid >> 6, j2 = tid & 63;
        float v2 = s_p2[hd2][0][j2] + s_p2[hd2][1][j2];
        float q1 = v2, q2s = v2 * v2;
        #pragma unroll
        for (int m = 1; m < 64; m <<= 1) { q1 += __shfl_xor(q1, m); q2s += __shfl_xor(q2s, m); }
        const float mean = q1 * (1.f / 64.f);
        const float var = q2s * (1.f / 64.f) - mean * mean;
        s_h2[hd2][j2] = fmaxf((v2 - mean) * rsqrtf(var + 1e-5f) * (hd2 ? vg2 : pg2)[j2]
                              + (hd2 ? vbt2 : pbt2)[j2], 0.f);
    }
    __syncthreads();

    // ---- output heads ----
    if (tid < 8) {
        const float4* w4 = (const float4*)(pWoT + tid * 64);
        const float4* h4 = (const float4*)s_h2[0];
        float v3 = pbo[tid];
        #pragma unroll
        for (int q = 0; q < 16; ++q) {
            float4 a = h4[q], w = w4[q];
            v3 += a.x * w.x + a.y * w.y + a.z * w.z + a.w * w.w;
        }
        dout[(size_t)b * 8 + tid] = v3;
    } else if (tid == 8) {
        const float4* w4 = (const float4*)vWo;   // [64][1] is contiguous
        const float4* h4 = (const float4*)s_h2[1];
        float v3 = vbo[0];
        #pragma unroll
        for (int q = 0; q < 16; ++q) {
            float4 a = h4[q], w = w4[q];
            v3 += a.x * w.x + a.y * w.y + a.z * w.z + a.w * w.w;
        }
        dout[(size_t)BB * 8 + b] = v3;
    }
}

extern "C" void kernel_launch(void* const* d_in, const int* in_sizes, int n_in,
                              void* d_out, int out_size, void* d_ws, size_t ws_size,
                              hipStream_t stream) {
    (void)in_sizes; (void)n_in; (void)out_size; (void)ws_size;
    const float* selfF  = (const float*)d_in[0];
    const float* nbF    = (const float*)d_in[1];
    const float* mask   = (const float*)d_in[2];
    const float* projW  = (const float*)d_in[3];
    const float* projB  = (const float*)d_in[4];
    const float* projG  = (const float*)d_in[5];
    const float* projBt = (const float*)d_in[6];
    const float* coopW  = (const float*)d_in[7];
    const float* coopS  = (const float*)d_in[8];
    const float* coopD  = (const float*)d_in[9];
    const float* confW  = (const float*)d_in[10];
    const float* confS  = (const float*)d_in[11];
    const float* confD  = (const float*)d_in[12];
    const float* sageW  = (const float*)d_in[13];
    const float* sageB  = (const float*)d_in[14];
    const float* gfWx = (const float*)d_in[15];
    const float* gfWh = (const float*)d_in[16];
    const float* gfbx = (const float*)d_in[17];
    const float* gfbh = (const float*)d_in[18];
    const float* gbWx = (const float*)d_in[19];
    const float* gbWh = (const float*)d_in[20];
    const float* gbbx = (const float*)d_in[21];
    const float* gbbh = (const float*)d_in[22];
    const float* pW1  = (const float*)d_in[23];
    const float* pb1  = (const float*)d_in[24];
    const float* pg1  = (const float*)d_in[25];
    const float* pbt1 = (const float*)d_in[26];
    const float* pW2  = (const float*)d_in[27];
    const float* pb2  = (const float*)d_in[28];
    const float* pg2  = (const float*)d_in[29];
    const float* pbt2 = (const float*)d_in[30];
    const float* pWo  = (const float*)d_in[31];
    const float* pbo  = (const float*)d_in[32];
    const float* vW1  = (const float*)d_in[33];
    const float* vb1  = (const float*)d_in[34];
    const float* vg1  = (const float*)d_in[35];
    const float* vbt1 = (const float*)d_in[36];
    const float* vW2  = (const float*)d_in[37];
    const float* vb2  = (const float*)d_in[38];
    const float* vg2  = (const float*)d_in[39];
    const float* vbt2 = (const float*)d_in[40];
    const float* vWo  = (const float*)d_in[41];
    const float* vbo  = (const float*)d_in[42];

    float* hsage   = (float*)d_ws;                                    // 1310720 f
    float* embLast = hsage + (size_t)BB * TT * SAGE_H;                // 1048576 f
    unsigned short* wt = (unsigned short*)(embLast + (size_t)BB * GAT_TOT); // 16384 us
    float* statc  = (float*)(wt + 256 * GH);                          // 20 f (pad 32)
    float* gfWxT  = statc + 32;                                       // 6144 f
    float* gbWxT  = gfWxT + 96 * 64;                                  // 6144 f
    float* pW1T   = gbWxT + 96 * 64;                                  // 40960 f
    float* vW1T   = pW1T + 128 * 320;                                 // 40960 f
    float* pW2T   = vW1T + 128 * 320;                                 // 8192 f
    float* vW2T   = pW2T + 64 * 128;                                  // 8192 f
    float* pWoT   = vW2T + 64 * 128;                                  // 512 f

    setup_kernel<<<1, 256, 0, stream>>>(coopW, confW, projW, projB,
                                        gfWx, gbWx, pW1, vW1, pW2, vW2, pWo,
                                        wt, statc, gfWxT, gbWxT,
                                        pW1T, vW1T, pW2T, vW2T, pWoT);

    gat_sage_kernel<<<BB * TT, 256, 0, stream>>>(
        selfF, nbF, mask, projW, projB, projG, projBt,
        coopS, coopD, confS, confD, wt, statc,
        sageW, sageB, hsage, embLast);

    gru_head_kernel<<<BB, 256, 0, stream>>>(
        hsage, embLast,
        gfWxT, gfWh, gfbx, gfbh, gbWxT, gbWh, gbbx, gbbh,
        pW1T, pb1, pg1, pbt1, pW2T, pb2, pg2, pbt2, pWoT, pbo,
        vW1T, vb1, vg1, vbt1, vW2T, vb2, vg2, vbt2, vWo, vbo,
        (float*)d_out);
}

// Round 11
// 762.521 us; speedup vs baseline: 1.3045x; 1.3045x over previous
//
#include <hip/hip_runtime.h>
#include <hip/hip_bf16.h>
#include <math.h>

#define BB 4096
#define TT 5
#define KK 4
#define NLANES 12
#define GH 64
#define GO 32
#define GAT_TOT 256
#define SAGE_H 64
#define GRU_H 32

typedef __attribute__((ext_vector_type(8))) short short8v;
typedef __attribute__((ext_vector_type(8))) unsigned short ushort8v;
typedef __attribute__((ext_vector_type(4))) unsigned short ushort4v;
typedef __attribute__((ext_vector_type(4))) float f32x4;

__device__ __forceinline__ unsigned short f2bf(float x) {
    __hip_bfloat16 h = __float2bfloat16(x);
    return __builtin_bit_cast(unsigned short, h);
}
__device__ __forceinline__ float bf2f(unsigned short b) {
    return __uint_as_float(((unsigned)b) << 16);
}

// ---------------------------------------------------------------------------
// Setup (2 blocks): block 0 -> wt bf16 [256][64] (W^T, one col per thread);
// block 1 -> statc[20] LN quadratic-form coefficients (one per thread).
// ---------------------------------------------------------------------------
__global__ void setup_kernel(const float* __restrict__ coopW,
                             const float* __restrict__ confW,
                             const float* __restrict__ projW,
                             const float* __restrict__ projB,
                             unsigned short* __restrict__ wt,
                             float* __restrict__ statc) {
    const int tnum = threadIdx.x;
    if (blockIdx.x == 0) {
        int c = tnum;
        int g = c >> 7, hh = (c >> 5) & 3, o = c & 31;
        const float* W = (g ? confW : coopW) + hh * (GH * GO) + o;
        for (int k = 0; k < GH; ++k)
            wt[c * GH + k] = f2bf(W[k * GO]);
    } else if (tnum < 20) {
        // per-thread: recompute means locally (L1-hot), then own coefficient
        float Wm[4], bm = 0.f;
        #pragma unroll
        for (int c = 0; c < 4; ++c) {
            float s = 0.f;
            for (int f = 0; f < GH; ++f) s += projW[c * GH + f];
            Wm[c] = s * (1.f / GH);
        }
        for (int f = 0; f < GH; ++f) bm += projB[f];
        bm *= (1.f / GH);

        float val;
        if (tnum < 10) {
            const int cs[10] = {0,0,0,0,1,1,1,2,2,3};
            const int ds[10] = {0,1,2,3,1,2,3,2,3,3};
            int c = cs[tnum], d = ds[tnum];
            float s = 0.f;
            for (int f = 0; f < GH; ++f)
                s += (projW[c * GH + f] - Wm[c]) * (projW[d * GH + f] - Wm[d]);
            val = s * (1.f / GH) * (c == d ? 1.f : 2.f);
        } else if (tnum < 14) {
            int c = tnum - 10;
            float s = 0.f;
            for (int f = 0; f < GH; ++f)
                s += (projW[c * GH + f] - Wm[c]) * (projB[f] - bm);
            val = s * (2.f / GH);
        } else if (tnum == 14) {
            float s = 0.f;
            for (int f = 0; f < GH; ++f)
                s += (projB[f] - bm) * (projB[f] - bm);
            val = s * (1.f / GH);
        } else if (tnum < 19) {
            val = Wm[tnum - 15];
        } else {
            val = bm;
        }
        statc[tnum] = val;
    }
}

// ---------------------------------------------------------------------------
// Kernel A: unchanged from round 10 (637 us, 4 blocks/CU, no spill).
// ---------------------------------------------------------------------------
__global__ __launch_bounds__(256, 4) void gat_sage_kernel(
    const float* __restrict__ selfF, const float* __restrict__ nbF,
    const float* __restrict__ mask,
    const float* __restrict__ projW, const float* __restrict__ projB,
    const float* __restrict__ projG, const float* __restrict__ projBt,
    const float* __restrict__ coopSrc, const float* __restrict__ coopDst,
    const float* __restrict__ confSrc, const float* __restrict__ confDst,
    const unsigned short* __restrict__ wt, const float* __restrict__ statc,
    const float* __restrict__ sageW, const float* __restrict__ sageB,
    float* __restrict__ hsage, float* __restrict__ embLast)
{
    __shared__ __align__(16) char s_all[40960];

    float* s_x = (float*)s_all;
    float2* s_stat = (float2*)(s_all + 1024);
    unsigned short* WhT = (unsigned short*)s_all;
    float (*s_att)[8][NLANES][16] = (float (*)[8][NLANES][16])s_all;
    float* s_in = (float*)s_all;
    float (*s_part)[SAGE_H] = (float (*)[SAGE_H])(s_all + 2048);
    unsigned short* s_hb = (unsigned short*)(s_all + 32768);
    float (*s_sd)[8][64] = (float (*)[8][64])(s_all + 32768);

    const int bid = blockIdx.x;          // b*T + t
    const int b = bid / TT, t = bid % TT;
    const int tid = threadIdx.x;

    const int gh = tid >> 5;
    const int wv = tid >> 6, f = tid & 63;
    const int l15 = f & 15, g4 = f >> 4;

    if (tid < 60) {
        int inst = tid / 12, j = tid % 12;
        const float* xp = (inst == 0)
            ? (selfF + (size_t)bid * 48)
            : (nbF + (size_t)((b * KK + (inst - 1)) * TT + t) * 48);
        float4 xv = ((const float4*)xp)[j];
        ((float4*)s_x)[tid] = xv;
        const float* sc = statc;
        float mean = xv.x * sc[15] + xv.y * sc[16] + xv.z * sc[17] + xv.w * sc[18] + sc[19];
        float var = sc[0] * xv.x * xv.x + sc[1] * xv.x * xv.y + sc[2] * xv.x * xv.z
                  + sc[3] * xv.x * xv.w + sc[4] * xv.y * xv.y + sc[5] * xv.y * xv.z
                  + sc[6] * xv.y * xv.w + sc[7] * xv.z * xv.z + sc[8] * xv.z * xv.w
                  + sc[9] * xv.w * xv.w
                  + sc[10] * xv.x + sc[11] * xv.y + sc[12] * xv.z + sc[13] * xv.w + sc[14];
        s_stat[tid] = make_float2(mean, rsqrtf(fmaxf(var, 0.f) + 1e-5f));
    }

    const float pw0 = projW[0 * GH + f], pw1 = projW[1 * GH + f];
    const float pw2 = projW[2 * GH + f], pw3 = projW[3 * GH + f];
    const float pb = projB[f], pg = projG[f], pbt = projBt[f];
    __syncthreads();

    #pragma unroll
    for (int i = 0; i < 15; ++i) {
        const int r = wv + i * 4;
        float2 st = s_stat[r];
        float h = fmaf(s_x[r * 4 + 0], pw0, fmaf(s_x[r * 4 + 1], pw1,
                  fmaf(s_x[r * 4 + 2], pw2, fmaf(s_x[r * 4 + 3], pw3, pb))));
        float nv = (h - st.x) * (st.y * pg) + pbt;
        nv = fmaxf(nv, 0.f);
        s_hb[r * 64 + (((f >> 3) ^ (r & 7)) << 3) + (f & 7)] = f2bf(nv);
    }
    {
        const int r = 60 + wv;
        s_hb[r * 64 + (((f >> 3) ^ (r & 7)) << 3) + (f & 7)] = 0;
    }
    __syncthreads();

    {
        f32x4 c[4][4];
        #pragma unroll
        for (int mt = 0; mt < 4; ++mt)
            #pragma unroll
            for (int nt = 0; nt < 4; ++nt)
                c[mt][nt] = (f32x4){0.f, 0.f, 0.f, 0.f};

        #pragma unroll
        for (int kt = 0; kt < 2; ++kt) {
            const int kc = kt * 4 + g4;
            short8v a[4], bfr[4];
            #pragma unroll
            for (int mt = 0; mt < 4; ++mt) {
                const int r = mt * 16 + l15;
                a[mt] = *(const short8v*)&s_hb[r * 64 + ((kc ^ (r & 7)) << 3)];
            }
            #pragma unroll
            for (int nt = 0; nt < 4; ++nt)
                bfr[nt] = *(const short8v*)&wt[(wv * 64 + nt * 16 + l15) * GH + kc * 8];
            #pragma unroll
            for (int mt = 0; mt < 4; ++mt)
                #pragma unroll
                for (int nt = 0; nt < 4; ++nt)
                    c[mt][nt] = __builtin_amdgcn_mfma_f32_16x16x32_bf16(
                        a[mt], bfr[nt], c[mt][nt], 0, 0, 0);
        }

        __syncthreads();   // s_hb reads done -> s_sd alias safe

        {
            float asv[4], adv[4];
            #pragma unroll
            for (int nt = 0; nt < 4; ++nt) {
                const int cc = wv * 64 + nt * 16 + l15;
                const int g = cc >> 7, hh = (cc >> 5) & 3, oo = cc & 31;
                asv[nt] = (g ? confSrc : coopSrc)[hh * GO + oo];
                adv[nt] = (g ? confDst : coopDst)[hh * GO + oo];
            }
            #pragma unroll
            for (int p = 0; p < 2; ++p) {
                const int ghw = 2 * wv + p;
                #pragma unroll
                for (int mt = 0; mt < 4; ++mt) {
                    float sv[4], dv[4];
                    #pragma unroll
                    for (int r = 0; r < 4; ++r) {
                        sv[r] = c[mt][2 * p][r] * asv[2 * p] + c[mt][2 * p + 1][r] * asv[2 * p + 1];
                        dv[r] = c[mt][2 * p][r] * adv[2 * p] + c[mt][2 * p + 1][r] * adv[2 * p + 1];
                    }
                    #pragma unroll
                    for (int m = 1; m < 16; m <<= 1) {
                        #pragma unroll
                        for (int r = 0; r < 4; ++r) {
                            sv[r] += __shfl_xor(sv[r], m);
                            dv[r] += __shfl_xor(dv[r], m);
                        }
                    }
                    if (l15 == 0) {
                        const int rb = mt * 16 + g4 * 4;
                        *(float4*)&s_sd[0][ghw][rb] = make_float4(sv[0], sv[1], sv[2], sv[3]);
                        *(float4*)&s_sd[1][ghw][rb] = make_float4(dv[0], dv[1], dv[2], dv[3]);
                    }
                }
            }
        }

        #pragma unroll
        for (int mt = 0; mt < 4; ++mt) {
            #pragma unroll
            for (int nt = 0; nt < 4; ++nt) {
                const int cc = wv * 64 + nt * 16 + l15;
                const int rb = mt * 16 + g4 * 4;
                ushort4v p;
                p.x = f2bf(c[mt][nt][0]); p.y = f2bf(c[mt][nt][1]);
                p.z = f2bf(c[mt][nt][2]); p.w = f2bf(c[mt][nt][3]);
                const int idx = cc * 64 + (((rb >> 3) ^ (cc & 7)) << 3) + (rb & 7);
                *(ushort4v*)&WhT[idx] = p;
            }
        }
    }
    __syncthreads();

    float acc[60];
    {
        const int cs = tid & 7;
        #pragma unroll
        for (int ch = 0; ch < 8; ++ch) {
            ushort8v v = *(const ushort8v*)&WhT[tid * 64 + ((ch ^ cs) << 3)];
            #pragma unroll
            for (int j = 0; j < 8; ++j) {
                const int r = ch * 8 + j;
                if (r < 60) acc[r] = bf2f(v[j]);
            }
        }
    }
    __syncthreads();

    #pragma unroll
    for (int round = 0; round < 2; ++round) {
        const int task = tid + round * 256;
        if (task < 480) {
            const int inst = task / 96;
            const int rem = task - inst * 96;
            const int gh2 = rem / 12, n2 = rem - (rem / 12) * 12;
            const int g2 = gh2 >> 2;
            const int an = n2 / 3;
            const float sn = s_sd[0][gh2][inst * 12 + n2];
            float vq[12];
            float mx = -1e30f;
            #pragma unroll
            for (int mm = 0; mm < NLANES; ++mm) {
                int am = mm / 3;
                bool valid = (g2 == 0) ? (am == an) : (am != an || mm == n2);
                float ev = sn + s_sd[1][gh2][inst * 12 + mm];
                ev = ev > 0.f ? ev : 0.2f * ev;
                vq[mm] = valid ? ev : -1e30f;
                mx = fmaxf(mx, vq[mm]);
            }
            float sum = 0.f;
            #pragma unroll
            for (int mm = 0; mm < NLANES; ++mm) {
                float ex = __expf(vq[mm] - mx);
                vq[mm] = ex; sum += ex;
            }
            const float inv = 1.f / sum;
            const int sw = n2 & 3;
            float4* arow = (float4*)s_att[inst][gh2][n2];
            arow[0 ^ sw] = make_float4(vq[0] * inv, vq[1] * inv, vq[2] * inv, vq[3] * inv);
            arow[1 ^ sw] = make_float4(vq[4] * inv, vq[5] * inv, vq[6] * inv, vq[7] * inv);
            arow[2 ^ sw] = make_float4(vq[8] * inv, vq[9] * inv, vq[10] * inv, vq[11] * inv);
        }
    }
    __syncthreads();

    {
        float pooled_arr[5];
        #pragma unroll
        for (int inst = 0; inst < 5; ++inst) {
            float pooled = 0.f;
            #pragma unroll
            for (int n = 0; n < NLANES; ++n) {
                const int sw = n & 3;
                const float4* arow = (const float4*)s_att[inst][gh][n];
                float4 a0 = arow[0 ^ sw], a1 = arow[1 ^ sw], a2 = arow[2 ^ sw];
                float v = a0.x * acc[inst * 12 + 0] + a0.y * acc[inst * 12 + 1]
                        + a0.z * acc[inst * 12 + 2] + a0.w * acc[inst * 12 + 3]
                        + a1.x * acc[inst * 12 + 4] + a1.y * acc[inst * 12 + 5]
                        + a1.z * acc[inst * 12 + 6] + a1.w * acc[inst * 12 + 7]
                        + a2.x * acc[inst * 12 + 8] + a2.y * acc[inst * 12 + 9]
                        + a2.z * acc[inst * 12 + 10] + a2.w * acc[inst * 12 + 11];
                v = v > 0.f ? v : (__expf(v) - 1.f);
                pooled += v;
            }
            pooled_arr[inst] = pooled * (1.f / 12.f);
        }
        __syncthreads();

        const float m0 = mask[b * KK + 0], m1 = mask[b * KK + 1];
        const float m2 = mask[b * KK + 2], m3 = mask[b * KK + 3];
        const float inv = 1.f / fmaxf(m0 + m1 + m2 + m3, 1.f);
        s_in[tid] = pooled_arr[0];
        s_in[GAT_TOT + tid] = (m0 * pooled_arr[1] + m1 * pooled_arr[2]
                             + m2 * pooled_arr[3] + m3 * pooled_arr[4]) * inv;
        if (t == TT - 1) embLast[(size_t)b * GAT_TOT + tid] = pooled_arr[0];
    }
    __syncthreads();

    {
        const int j = tid & 63, q = tid >> 6;
        const float4* si4 = (const float4*)s_in;
        float v = 0.f;
        #pragma unroll 8
        for (int cq = q * 32; cq < q * 32 + 32; ++cq) {
            float4 s4 = si4[cq];
            const float* Wp = sageW + (cq * 4) * SAGE_H + j;
            v += s4.x * Wp[0] + s4.y * Wp[SAGE_H] + s4.z * Wp[2 * SAGE_H] + s4.w * Wp[3 * SAGE_H];
        }
        s_part[q][j] = v;
    }
    __syncthreads();
    if (tid < SAGE_H) {
        float v = sageB[tid] + s_part[0][tid] + s_part[1][tid]
                + s_part[2][tid] + s_part[3][tid];
        hsage[(size_t)bid * SAGE_H + tid] = fmaxf(v, 0.f);
    }
}

// ---------------------------------------------------------------------------
// Kernel B: parallel MLP heads, ORIGINAL column-major (lane-coalesced) weights.
// ---------------------------------------------------------------------------
__global__ __launch_bounds__(256) void gru_head_kernel(
    const float* __restrict__ hsage, const float* __restrict__ embLast,
    const float* __restrict__ gfWx, const float* __restrict__ gfWh,
    const float* __restrict__ gfbx, const float* __restrict__ gfbh,
    const float* __restrict__ gbWx, const float* __restrict__ gbWh,
    const float* __restrict__ gbbx, const float* __restrict__ gbbh,
    const float* __restrict__ pW1, const float* __restrict__ pb1,
    const float* __restrict__ pg1, const float* __restrict__ pbt1,
    const float* __restrict__ pW2, const float* __restrict__ pb2,
    const float* __restrict__ pg2, const float* __restrict__ pbt2,
    const float* __restrict__ pWo, const float* __restrict__ pbo,
    const float* __restrict__ vW1, const float* __restrict__ vb1,
    const float* __restrict__ vg1, const float* __restrict__ vbt1,
    const float* __restrict__ vW2, const float* __restrict__ vb2,
    const float* __restrict__ vg2, const float* __restrict__ vbt2,
    const float* __restrict__ vWo, const float* __restrict__ vbo,
    float* __restrict__ dout)
{
    __shared__ __align__(16) float s_seq[TT * SAGE_H];
    __shared__ float s_gx[2][TT][96];
    __shared__ float s_hh[2][GRU_H];
    __shared__ __align__(16) float s_joint[320];
    __shared__ __align__(16) float s_h1[2][128];
    __shared__ __align__(16) float s_h2[2][64];
    __shared__ float s_p2[2][2][64];
    __shared__ float s_red[8];

    const int b = blockIdx.x, tid = threadIdx.x;

    if (tid < 80) ((float4*)s_seq)[tid] = ((const float4*)(hsage + (size_t)b * TT * SAGE_H))[tid];
    s_joint[tid] = embLast[(size_t)b * GAT_TOT + tid];
    if (tid < 64) s_hh[tid >> 5][tid & 31] = 0.f;
    __syncthreads();

    // gx precompute: column-major Wx (lane-coalesced)
    for (int task = tid; task < 960; task += 256) {
        const int dir = task >= 480;
        const int rem = task - dir * 480;
        const int t5 = rem / 96, j = rem - t5 * 96;
        const float* Wx = dir ? gbWx : gfWx;
        const float* x = &s_seq[t5 * SAGE_H];
        float v = (dir ? gbbx : gfbx)[j];
        for (int f2 = 0; f2 < SAGE_H; ++f2) v += x[f2] * Wx[f2 * 96 + j];
        s_gx[dir][t5][j] = v;
    }
    __syncthreads();

    // serial GRU (h-part only)
    for (int s = 0; s < TT; ++s) {
        float hnew = 0.f;
        if (tid < 64) {
            int dir = tid >> 5, j = tid & 31;
            int t5 = dir ? (TT - 1 - s) : s;
            const float* Wh = dir ? gbWh : gfWh;
            const float* bh = dir ? gbbh : gfbh;
            const float* h = s_hh[dir];
            float hr = bh[j], hz = bh[32 + j], hn = bh[64 + j];
            for (int k = 0; k < GRU_H; ++k) {
                float hv = h[k];
                hr += hv * Wh[k * 96 + j];
                hz += hv * Wh[k * 96 + 32 + j];
                hn += hv * Wh[k * 96 + 64 + j];
            }
            float xr = s_gx[dir][t5][j], xz = s_gx[dir][t5][32 + j], xn = s_gx[dir][t5][64 + j];
            float r = 1.f / (1.f + __expf(-(xr + hr)));
            float z = 1.f / (1.f + __expf(-(xz + hz)));
            float nn = tanhf(xn + r * hn);
            hnew = (1.f - z) * nn + z * h[j];
        }
        __syncthreads();
        if (tid < 64) s_hh[tid >> 5][tid & 31] = hnew;
        __syncthreads();
    }
    if (tid < 64) s_joint[GAT_TOT + tid] = s_hh[tid >> 5][tid & 31];
    __syncthreads();

    // ---- MLP layer 1: both heads concurrently; thread = hd*128 + j1 ----
    const int hd = tid >> 7, j1 = tid & 127;
    float v1;
    {
        const float* W1 = hd ? vW1 : pW1;
        v1 = (hd ? vb1 : pb1)[j1];
        for (int c2 = 0; c2 < 320; ++c2)
            v1 += s_joint[c2] * W1[c2 * 128 + j1];
    }
    {
        float q1 = v1, q2 = v1 * v1;
        #pragma unroll
        for (int m = 1; m < 64; m <<= 1) { q1 += __shfl_xor(q1, m); q2 += __shfl_xor(q2, m); }
        if ((tid & 63) == 0) { s_red[(tid >> 6) * 2] = q1; s_red[(tid >> 6) * 2 + 1] = q2; }
    }
    __syncthreads();
    {
        const float sum1 = s_red[4 * hd] + s_red[4 * hd + 2];
        const float sum2 = s_red[4 * hd + 1] + s_red[4 * hd + 3];
        const float mean = sum1 * (1.f / 128.f);
        const float var = sum2 * (1.f / 128.f) - mean * mean;
        v1 = fmaxf((v1 - mean) * rsqrtf(var + 1e-5f) * (hd ? vg1 : pg1)[j1]
                   + (hd ? vbt1 : pbt1)[j1], 0.f);
        s_h1[hd][j1] = v1;
    }
    __syncthreads();

    // ---- layer 2: thread = hd*128 + qq*64 + j2, split-K 2, col-major W2 ----
    {
        const int hd2 = tid >> 7, qq = (tid >> 6) & 1, j2 = tid & 63;
        const float* W2 = hd2 ? vW2 : pW2;
        float v2 = (qq == 0) ? (hd2 ? vb2 : pb2)[j2] : 0.f;
        for (int c2 = qq * 64; c2 < qq * 64 + 64; ++c2)
            v2 += s_h1[hd2][c2] * W2[c2 * 64 + j2];
        s_p2[hd2][qq][j2] = v2;
    }
    __syncthreads();
    if (tid < 128) {
        const int hd2 = tid >> 6, j2 = tid & 63;
        float v2 = s_p2[hd2][0][j2] + s_p2[hd2][1][j2];
        float q1 = v2, q2s = v2 * v2;
        #pragma unroll
        for (int m = 1; m < 64; m <<= 1) { q1 += __shfl_xor(q1, m); q2s += __shfl_xor(q2s, m); }
        const float mean = q1 * (1.f / 64.f);
        const float var = q2s * (1.f / 64.f) - mean * mean;
        s_h2[hd2][j2] = fmaxf((v2 - mean) * rsqrtf(var + 1e-5f) * (hd2 ? vg2 : pg2)[j2]
                              + (hd2 ? vbt2 : pbt2)[j2], 0.f);
    }
    __syncthreads();

    // ---- output heads ----
    if (tid < 8) {
        float v3 = pbo[tid];
        for (int c2 = 0; c2 < 64; ++c2) v3 += s_h2[0][c2] * pWo[c2 * 8 + tid];
        dout[(size_t)b * 8 + tid] = v3;
    } else if (tid == 8) {
        const float4* w4 = (const float4*)vWo;   // [64][1] contiguous
        const float4* h4 = (const float4*)s_h2[1];
        float v3 = vbo[0];
        #pragma unroll
        for (int q = 0; q < 16; ++q) {
            float4 a = h4[q], w = w4[q];
            v3 += a.x * w.x + a.y * w.y + a.z * w.z + a.w * w.w;
        }
        dout[(size_t)BB * 8 + b] = v3;
    }
}

extern "C" void kernel_launch(void* const* d_in, const int* in_sizes, int n_in,
                              void* d_out, int out_size, void* d_ws, size_t ws_size,
                              hipStream_t stream) {
    (void)in_sizes; (void)n_in; (void)out_size; (void)ws_size;
    const float* selfF  = (const float*)d_in[0];
    const float* nbF    = (const float*)d_in[1];
    const float* mask   = (const float*)d_in[2];
    const float* projW  = (const float*)d_in[3];
    const float* projB  = (const float*)d_in[4];
    const float* projG  = (const float*)d_in[5];
    const float* projBt = (const float*)d_in[6];
    const float* coopW  = (const float*)d_in[7];
    const float* coopS  = (const float*)d_in[8];
    const float* coopD  = (const float*)d_in[9];
    const float* confW  = (const float*)d_in[10];
    const float* confS  = (const float*)d_in[11];
    const float* confD  = (const float*)d_in[12];
    const float* sageW  = (const float*)d_in[13];
    const float* sageB  = (const float*)d_in[14];
    const float* gfWx = (const float*)d_in[15];
    const float* gfWh = (const float*)d_in[16];
    const float* gfbx = (const float*)d_in[17];
    const float* gfbh = (const float*)d_in[18];
    const float* gbWx = (const float*)d_in[19];
    const float* gbWh = (const float*)d_in[20];
    const float* gbbx = (const float*)d_in[21];
    const float* gbbh = (const float*)d_in[22];
    const float* pW1  = (const float*)d_in[23];
    const float* pb1  = (const float*)d_in[24];
    const float* pg1  = (const float*)d_in[25];
    const float* pbt1 = (const float*)d_in[26];
    const float* pW2  = (const float*)d_in[27];
    const float* pb2  = (const float*)d_in[28];
    const float* pg2  = (const float*)d_in[29];
    const float* pbt2 = (const float*)d_in[30];
    const float* pWo  = (const float*)d_in[31];
    const float* pbo  = (const float*)d_in[32];
    const float* vW1  = (const float*)d_in[33];
    const float* vb1  = (const float*)d_in[34];
    const float* vg1  = (const float*)d_in[35];
    const float* vbt1 = (const float*)d_in[36];
    const float* vW2  = (const float*)d_in[37];
    const float* vb2  = (const float*)d_in[38];
    const float* vg2  = (const float*)d_in[39];
    const float* vbt2 = (const float*)d_in[40];
    const float* vWo  = (const float*)d_in[41];
    const float* vbo  = (const float*)d_in[42];

    float* hsage   = (float*)d_ws;                                    // B*T*64 f32
    float* embLast = hsage + (size_t)BB * TT * SAGE_H;                // B*256 f32
    unsigned short* wt = (unsigned short*)(embLast + (size_t)BB * GAT_TOT); // [256][64] bf16
    float* statc = (float*)(wt + 256 * GH);                           // [20] f32

    setup_kernel<<<2, 256, 0, stream>>>(coopW, confW, projW, projB, wt, statc);

    gat_sage_kernel<<<BB * TT, 256, 0, stream>>>(
        selfF, nbF, mask, projW, projB, projG, projBt,
        coopS, coopD, confS, confD, wt, statc,
        sageW, sageB, hsage, embLast);

    gru_head_kernel<<<BB, 256, 0, stream>>>(
        hsage, embLast,
        gfWx, gfWh, gfbx, gfbh, gbWx, gbWh, gbbx, gbbh,
        pW1, pb1, pg1, pbt1, pW2, pb2, pg2, pbt2, pWo, pbo,
        vW1, vb1, vg1, vbt1, vW2, vb2, vg2, vbt2, vWo, vbo,
        (float*)d_out);
}

// Round 12
// 535.237 us; speedup vs baseline: 1.8584x; 1.4246x over previous
//
#include <hip/hip_runtime.h>
#include <hip/hip_bf16.h>
#include <math.h>

#define BB 4096
#define TT 5
#define KK 4
#define NLANES 12
#define GH 64
#define GO 32
#define GAT_TOT 256
#define SAGE_H 64
#define GRU_H 32
#define BT 4

typedef __attribute__((ext_vector_type(8))) short short8v;
typedef __attribute__((ext_vector_type(8))) unsigned short ushort8v;
typedef __attribute__((ext_vector_type(4))) unsigned short ushort4v;
typedef __attribute__((ext_vector_type(4))) float f32x4;

__device__ __forceinline__ unsigned short f2bf(float x) {
    __hip_bfloat16 h = __float2bfloat16(x);
    return __builtin_bit_cast(unsigned short, h);
}
__device__ __forceinline__ float bf2f(unsigned short b) {
    return __uint_as_float(((unsigned)b) << 16);
}

// ---------------------------------------------------------------------------
// Setup (2 blocks): block 0 -> wt bf16 [256][64]; block 1 -> statc[20].
// ---------------------------------------------------------------------------
__global__ void setup_kernel(const float* __restrict__ coopW,
                             const float* __restrict__ confW,
                             const float* __restrict__ projW,
                             const float* __restrict__ projB,
                             unsigned short* __restrict__ wt,
                             float* __restrict__ statc) {
    const int tnum = threadIdx.x;
    if (blockIdx.x == 0) {
        int c = tnum;
        int g = c >> 7, hh = (c >> 5) & 3, o = c & 31;
        const float* W = (g ? confW : coopW) + hh * (GH * GO) + o;
        for (int k = 0; k < GH; ++k)
            wt[c * GH + k] = f2bf(W[k * GO]);
    } else if (tnum < 20) {
        float Wm[4], bm = 0.f;
        #pragma unroll
        for (int c = 0; c < 4; ++c) {
            float s = 0.f;
            for (int f = 0; f < GH; ++f) s += projW[c * GH + f];
            Wm[c] = s * (1.f / GH);
        }
        for (int f = 0; f < GH; ++f) bm += projB[f];
        bm *= (1.f / GH);

        float val;
        if (tnum < 10) {
            const int cs[10] = {0,0,0,0,1,1,1,2,2,3};
            const int ds[10] = {0,1,2,3,1,2,3,2,3,3};
            int c = cs[tnum], d = ds[tnum];
            float s = 0.f;
            for (int f = 0; f < GH; ++f)
                s += (projW[c * GH + f] - Wm[c]) * (projW[d * GH + f] - Wm[d]);
            val = s * (1.f / GH) * (c == d ? 1.f : 2.f);
        } else if (tnum < 14) {
            int c = tnum - 10;
            float s = 0.f;
            for (int f = 0; f < GH; ++f)
                s += (projW[c * GH + f] - Wm[c]) * (projB[f] - bm);
            val = s * (2.f / GH);
        } else if (tnum == 14) {
            float s = 0.f;
            for (int f = 0; f < GH; ++f)
                s += (projB[f] - bm) * (projB[f] - bm);
            val = s * (1.f / GH);
        } else if (tnum < 19) {
            val = Wm[tnum - 15];
        } else {
            val = bm;
        }
        statc[tnum] = val;
    }
}

// ---------------------------------------------------------------------------
// Kernel A: r11 + sparsity-specialized pool (coop 3-term / conf 10-term,
// wave-uniform split) + dwordx4 sage loads.
// ---------------------------------------------------------------------------
__global__ __launch_bounds__(256, 4) void gat_sage_kernel(
    const float* __restrict__ selfF, const float* __restrict__ nbF,
    const float* __restrict__ mask,
    const float* __restrict__ projW, const float* __restrict__ projB,
    const float* __restrict__ projG, const float* __restrict__ projBt,
    const float* __restrict__ coopSrc, const float* __restrict__ coopDst,
    const float* __restrict__ confSrc, const float* __restrict__ confDst,
    const unsigned short* __restrict__ wt, const float* __restrict__ statc,
    const float* __restrict__ sageW, const float* __restrict__ sageB,
    float* __restrict__ hsage, float* __restrict__ embLast)
{
    __shared__ __align__(16) char s_all[40960];

    float* s_x = (float*)s_all;
    float2* s_stat = (float2*)(s_all + 1024);
    unsigned short* WhT = (unsigned short*)s_all;
    float (*s_att)[8][NLANES][16] = (float (*)[8][NLANES][16])s_all;
    float* s_in = (float*)s_all;
    float (*s_part)[SAGE_H] = (float (*)[SAGE_H])(s_all + 2048);   // [16][64]
    unsigned short* s_hb = (unsigned short*)(s_all + 32768);
    float (*s_sd)[8][64] = (float (*)[8][64])(s_all + 32768);

    const int bid = blockIdx.x;          // b*T + t
    const int b = bid / TT, t = bid % TT;
    const int tid = threadIdx.x;

    const int gh = tid >> 5;
    const int wv = tid >> 6, f = tid & 63;
    const int l15 = f & 15, g4 = f >> 4;

    if (tid < 60) {
        int inst = tid / 12, j = tid % 12;
        const float* xp = (inst == 0)
            ? (selfF + (size_t)bid * 48)
            : (nbF + (size_t)((b * KK + (inst - 1)) * TT + t) * 48);
        float4 xv = ((const float4*)xp)[j];
        ((float4*)s_x)[tid] = xv;
        const float* sc = statc;
        float mean = xv.x * sc[15] + xv.y * sc[16] + xv.z * sc[17] + xv.w * sc[18] + sc[19];
        float var = sc[0] * xv.x * xv.x + sc[1] * xv.x * xv.y + sc[2] * xv.x * xv.z
                  + sc[3] * xv.x * xv.w + sc[4] * xv.y * xv.y + sc[5] * xv.y * xv.z
                  + sc[6] * xv.y * xv.w + sc[7] * xv.z * xv.z + sc[8] * xv.z * xv.w
                  + sc[9] * xv.w * xv.w
                  + sc[10] * xv.x + sc[11] * xv.y + sc[12] * xv.z + sc[13] * xv.w + sc[14];
        s_stat[tid] = make_float2(mean, rsqrtf(fmaxf(var, 0.f) + 1e-5f));
    }

    const float pw0 = projW[0 * GH + f], pw1 = projW[1 * GH + f];
    const float pw2 = projW[2 * GH + f], pw3 = projW[3 * GH + f];
    const float pb = projB[f], pg = projG[f], pbt = projBt[f];
    __syncthreads();

    #pragma unroll
    for (int i = 0; i < 15; ++i) {
        const int r = wv + i * 4;
        float2 st = s_stat[r];
        float h = fmaf(s_x[r * 4 + 0], pw0, fmaf(s_x[r * 4 + 1], pw1,
                  fmaf(s_x[r * 4 + 2], pw2, fmaf(s_x[r * 4 + 3], pw3, pb))));
        float nv = (h - st.x) * (st.y * pg) + pbt;
        nv = fmaxf(nv, 0.f);
        s_hb[r * 64 + (((f >> 3) ^ (r & 7)) << 3) + (f & 7)] = f2bf(nv);
    }
    {
        const int r = 60 + wv;
        s_hb[r * 64 + (((f >> 3) ^ (r & 7)) << 3) + (f & 7)] = 0;
    }
    __syncthreads();

    {
        f32x4 c[4][4];
        #pragma unroll
        for (int mt = 0; mt < 4; ++mt)
            #pragma unroll
            for (int nt = 0; nt < 4; ++nt)
                c[mt][nt] = (f32x4){0.f, 0.f, 0.f, 0.f};

        #pragma unroll
        for (int kt = 0; kt < 2; ++kt) {
            const int kc = kt * 4 + g4;
            short8v a[4], bfr[4];
            #pragma unroll
            for (int mt = 0; mt < 4; ++mt) {
                const int r = mt * 16 + l15;
                a[mt] = *(const short8v*)&s_hb[r * 64 + ((kc ^ (r & 7)) << 3)];
            }
            #pragma unroll
            for (int nt = 0; nt < 4; ++nt)
                bfr[nt] = *(const short8v*)&wt[(wv * 64 + nt * 16 + l15) * GH + kc * 8];
            #pragma unroll
            for (int mt = 0; mt < 4; ++mt)
                #pragma unroll
                for (int nt = 0; nt < 4; ++nt)
                    c[mt][nt] = __builtin_amdgcn_mfma_f32_16x16x32_bf16(
                        a[mt], bfr[nt], c[mt][nt], 0, 0, 0);
        }

        __syncthreads();   // s_hb reads done -> s_sd alias safe

        {
            float asv[4], adv[4];
            #pragma unroll
            for (int nt = 0; nt < 4; ++nt) {
                const int cc = wv * 64 + nt * 16 + l15;
                const int g = cc >> 7, hh = (cc >> 5) & 3, oo = cc & 31;
                asv[nt] = (g ? confSrc : coopSrc)[hh * GO + oo];
                adv[nt] = (g ? confDst : coopDst)[hh * GO + oo];
            }
            #pragma unroll
            for (int p = 0; p < 2; ++p) {
                const int ghw = 2 * wv + p;
                #pragma unroll
                for (int mt = 0; mt < 4; ++mt) {
                    float sv[4], dv[4];
                    #pragma unroll
                    for (int r = 0; r < 4; ++r) {
                        sv[r] = c[mt][2 * p][r] * asv[2 * p] + c[mt][2 * p + 1][r] * asv[2 * p + 1];
                        dv[r] = c[mt][2 * p][r] * adv[2 * p] + c[mt][2 * p + 1][r] * adv[2 * p + 1];
                    }
                    #pragma unroll
                    for (int m = 1; m < 16; m <<= 1) {
                        #pragma unroll
                        for (int r = 0; r < 4; ++r) {
                            sv[r] += __shfl_xor(sv[r], m);
                            dv[r] += __shfl_xor(dv[r], m);
                        }
                    }
                    if (l15 == 0) {
                        const int rb = mt * 16 + g4 * 4;
                        *(float4*)&s_sd[0][ghw][rb] = make_float4(sv[0], sv[1], sv[2], sv[3]);
                        *(float4*)&s_sd[1][ghw][rb] = make_float4(dv[0], dv[1], dv[2], dv[3]);
                    }
                }
            }
        }

        #pragma unroll
        for (int mt = 0; mt < 4; ++mt) {
            #pragma unroll
            for (int nt = 0; nt < 4; ++nt) {
                const int cc = wv * 64 + nt * 16 + l15;
                const int rb = mt * 16 + g4 * 4;
                ushort4v p;
                p.x = f2bf(c[mt][nt][0]); p.y = f2bf(c[mt][nt][1]);
                p.z = f2bf(c[mt][nt][2]); p.w = f2bf(c[mt][nt][3]);
                const int idx = cc * 64 + (((rb >> 3) ^ (cc & 7)) << 3) + (rb & 7);
                *(ushort4v*)&WhT[idx] = p;
            }
        }
    }
    __syncthreads();

    float acc[60];
    {
        const int cs = tid & 7;
        #pragma unroll
        for (int ch = 0; ch < 8; ++ch) {
            ushort8v v = *(const ushort8v*)&WhT[tid * 64 + ((ch ^ cs) << 3)];
            #pragma unroll
            for (int j = 0; j < 8; ++j) {
                const int r = ch * 8 + j;
                if (r < 60) acc[r] = bf2f(v[j]);
            }
        }
    }
    __syncthreads();

    #pragma unroll
    for (int round = 0; round < 2; ++round) {
        const int task = tid + round * 256;
        if (task < 480) {
            const int inst = task / 96;
            const int rem = task - inst * 96;
            const int gh2 = rem / 12, n2 = rem - (rem / 12) * 12;
            const int g2 = gh2 >> 2;
            const int an = n2 / 3;
            const float sn = s_sd[0][gh2][inst * 12 + n2];
            float vq[12];
            float mx = -1e30f;
            #pragma unroll
            for (int mm = 0; mm < NLANES; ++mm) {
                int am = mm / 3;
                bool valid = (g2 == 0) ? (am == an) : (am != an || mm == n2);
                float ev = sn + s_sd[1][gh2][inst * 12 + mm];
                ev = ev > 0.f ? ev : 0.2f * ev;
                vq[mm] = valid ? ev : -1e30f;
                mx = fmaxf(mx, vq[mm]);
            }
            float sum = 0.f;
            #pragma unroll
            for (int mm = 0; mm < NLANES; ++mm) {
                float ex = __expf(vq[mm] - mx);
                vq[mm] = ex; sum += ex;
            }
            const float inv = 1.f / sum;
            const int sw = n2 & 3;
            float4* arow = (float4*)s_att[inst][gh2][n2];
            arow[0 ^ sw] = make_float4(vq[0] * inv, vq[1] * inv, vq[2] * inv, vq[3] * inv);
            arow[1 ^ sw] = make_float4(vq[4] * inv, vq[5] * inv, vq[6] * inv, vq[7] * inv);
            arow[2 ^ sw] = make_float4(vq[8] * inv, vq[9] * inv, vq[10] * inv, vq[11] * inv);
        }
    }
    __syncthreads();

    // ---- pool: sparsity-specialized (coop waves 3-term, conf 10-term) ----
    {
        float pooled_arr[5];
        if (wv < 2) {
            // coop: att[n] nonzero only at m in approach block an = n/3
            #pragma unroll
            for (int inst = 0; inst < 5; ++inst) {
                float pooled = 0.f;
                #pragma unroll
                for (int n = 0; n < NLANES; ++n) {
                    const int an = n / 3;
                    const int sw = n & 3;
                    const float4* arow = (const float4*)s_att[inst][gh][n];
                    float v;
                    if (an == 0) {
                        float4 a0 = arow[0 ^ sw];
                        v = a0.x * acc[inst * 12 + 0] + a0.y * acc[inst * 12 + 1]
                          + a0.z * acc[inst * 12 + 2];
                    } else if (an == 1) {
                        float4 a0 = arow[0 ^ sw], a1 = arow[1 ^ sw];
                        v = a0.w * acc[inst * 12 + 3] + a1.x * acc[inst * 12 + 4]
                          + a1.y * acc[inst * 12 + 5];
                    } else if (an == 2) {
                        float4 a1 = arow[1 ^ sw], a2 = arow[2 ^ sw];
                        v = a1.z * acc[inst * 12 + 6] + a1.w * acc[inst * 12 + 7]
                          + a2.x * acc[inst * 12 + 8];
                    } else {
                        float4 a2 = arow[2 ^ sw];
                        v = a2.y * acc[inst * 12 + 9] + a2.z * acc[inst * 12 + 10]
                          + a2.w * acc[inst * 12 + 11];
                    }
                    v = v > 0.f ? v : (__expf(v) - 1.f);
                    pooled += v;
                }
                pooled_arr[inst] = pooled * (1.f / 12.f);
            }
        } else {
            // conf: all entries except the 2 same-approach non-self (zeros)
            #pragma unroll
            for (int inst = 0; inst < 5; ++inst) {
                float pooled = 0.f;
                #pragma unroll
                for (int n = 0; n < NLANES; ++n) {
                    const int sw = n & 3;
                    const float4* arow = (const float4*)s_att[inst][gh][n];
                    float4 q0 = arow[0 ^ sw], q1 = arow[1 ^ sw], q2 = arow[2 ^ sw];
                    const float av[12] = {q0.x, q0.y, q0.z, q0.w,
                                          q1.x, q1.y, q1.z, q1.w,
                                          q2.x, q2.y, q2.z, q2.w};
                    float v = 0.f;
                    #pragma unroll
                    for (int m = 0; m < 12; ++m) {
                        if (m / 3 == n / 3 && m != n) continue;   // static zero-skip
                        v += av[m] * acc[inst * 12 + m];
                    }
                    v = v > 0.f ? v : (__expf(v) - 1.f);
                    pooled += v;
                }
                pooled_arr[inst] = pooled * (1.f / 12.f);
            }
        }
        __syncthreads();   // att dead

        const float m0 = mask[b * KK + 0], m1 = mask[b * KK + 1];
        const float m2 = mask[b * KK + 2], m3 = mask[b * KK + 3];
        const float inv = 1.f / fmaxf(m0 + m1 + m2 + m3, 1.f);
        s_in[tid] = pooled_arr[0];
        s_in[GAT_TOT + tid] = (m0 * pooled_arr[1] + m1 * pooled_arr[2]
                             + m2 * pooled_arr[3] + m3 * pooled_arr[4]) * inv;
        if (t == TT - 1) embLast[(size_t)b * GAT_TOT + tid] = pooled_arr[0];
    }
    __syncthreads();

    // ---- sage: thread=(q,j4), dwordx4 weight loads, 16-way split-K ----
    {
        const int q = tid >> 4, j4 = (tid & 15) << 2;
        const float4* si4 = (const float4*)s_in;
        float v0 = 0.f, v1 = 0.f, v2 = 0.f, v3 = 0.f;
        #pragma unroll 4
        for (int c4 = q * 8; c4 < q * 8 + 8; ++c4) {
            float4 s4 = si4[c4];
            const float* Wp = sageW + (c4 * 4) * SAGE_H + j4;
            float4 w;
            w = *(const float4*)(Wp);
            v0 = fmaf(s4.x, w.x, v0); v1 = fmaf(s4.x, w.y, v1);
            v2 = fmaf(s4.x, w.z, v2); v3 = fmaf(s4.x, w.w, v3);
            w = *(const float4*)(Wp + SAGE_H);
            v0 = fmaf(s4.y, w.x, v0); v1 = fmaf(s4.y, w.y, v1);
            v2 = fmaf(s4.y, w.z, v2); v3 = fmaf(s4.y, w.w, v3);
            w = *(const float4*)(Wp + 2 * SAGE_H);
            v0 = fmaf(s4.z, w.x, v0); v1 = fmaf(s4.z, w.y, v1);
            v2 = fmaf(s4.z, w.z, v2); v3 = fmaf(s4.z, w.w, v3);
            w = *(const float4*)(Wp + 3 * SAGE_H);
            v0 = fmaf(s4.w, w.x, v0); v1 = fmaf(s4.w, w.y, v1);
            v2 = fmaf(s4.w, w.z, v2); v3 = fmaf(s4.w, w.w, v3);
        }
        *(float4*)&s_part[q][j4] = make_float4(v0, v1, v2, v3);
    }
    __syncthreads();
    if (tid < SAGE_H) {
        float v = sageB[tid];
        #pragma unroll
        for (int q = 0; q < 16; ++q) v += s_part[q][tid];
        hsage[(size_t)bid * SAGE_H + tid] = fmaxf(v, 0.f);
    }
}

// ---------------------------------------------------------------------------
// Kernel B: BATCH=4 b's per block. Transposed joint [c][4] so each weight
// load feeds 4 fma; weight L2 traffic /4; GRU uses all 256 threads.
// ---------------------------------------------------------------------------
__global__ __launch_bounds__(256) void gru_head_kernel(
    const float* __restrict__ hsage, const float* __restrict__ embLast,
    const float* __restrict__ gfWx, const float* __restrict__ gfWh,
    const float* __restrict__ gfbx, const float* __restrict__ gfbh,
    const float* __restrict__ gbWx, const float* __restrict__ gbWh,
    const float* __restrict__ gbbx, const float* __restrict__ gbbh,
    const float* __restrict__ pW1, const float* __restrict__ pb1,
    const float* __restrict__ pg1, const float* __restrict__ pbt1,
    const float* __restrict__ pW2, const float* __restrict__ pb2,
    const float* __restrict__ pg2, const float* __restrict__ pbt2,
    const float* __restrict__ pWo, const float* __restrict__ pbo,
    const float* __restrict__ vW1, const float* __restrict__ vb1,
    const float* __restrict__ vg1, const float* __restrict__ vbt1,
    const float* __restrict__ vW2, const float* __restrict__ vb2,
    const float* __restrict__ vg2, const float* __restrict__ vbt2,
    const float* __restrict__ vWo, const float* __restrict__ vbo,
    float* __restrict__ dout)
{
    __shared__ __align__(16) float s_seq[BT][TT * SAGE_H];   // 5120 B
    __shared__ float s_gx[BT][2][TT][96];                    // 15360 B
    __shared__ float s_hh[BT][2][GRU_H];                     // 1024 B
    __shared__ __align__(16) float s_jt[320][BT];            // 5120 B
    __shared__ __align__(16) float s_h1[2][128][BT];         // 4096 B
    __shared__ __align__(16) float s_p2b[2][64][BT];         // 2048 B
    __shared__ __align__(16) float s_h2[2][64][BT];          // 2048 B
    __shared__ float s_red[2][2][BT][2];                     // 128 B

    const int b0 = blockIdx.x * BT;
    const int tid = threadIdx.x;

    for (int i = tid; i < BT * 80; i += 256) {
        int b = i / 80, qq = i - (i / 80) * 80;
        ((float4*)s_seq[b])[qq] =
            ((const float4*)(hsage + (size_t)(b0 + b) * (TT * SAGE_H)))[qq];
    }
    for (int i = tid; i < BT * 256; i += 256) {
        int b = i >> 8, c = i & 255;
        s_jt[c][b] = embLast[(size_t)(b0 + b) * GAT_TOT + c];
    }
    if (tid < BT * 64) s_hh[tid >> 6][(tid >> 5) & 1][tid & 31] = 0.f;
    __syncthreads();

    // gx: 4b x 2dir x 5t x 96j = 3840 tasks
    for (int task = tid; task < BT * 960; task += 256) {
        const int b = task / 960, rem = task - b * 960;
        const int dir = rem >= 480, rem2 = rem - dir * 480;
        const int t5 = rem2 / 96, j = rem2 - t5 * 96;
        const float* Wx = dir ? gbWx : gfWx;
        const float* x = s_seq[b] + t5 * SAGE_H;
        float v = (dir ? gbbx : gfbx)[j];
        for (int f2 = 0; f2 < SAGE_H; ++f2) v += x[f2] * Wx[f2 * 96 + j];
        s_gx[b][dir][t5][j] = v;
    }
    __syncthreads();

    // GRU serial: thread (b, dir, j) -> all 256 threads active
    {
        const int b = tid >> 6, dir = (tid >> 5) & 1, j = tid & 31;
        const float* Wh = dir ? gbWh : gfWh;
        const float* bh = dir ? gbbh : gfbh;
        for (int s = 0; s < TT; ++s) {
            const int t5 = dir ? (TT - 1 - s) : s;
            const float* h = s_hh[b][dir];
            float hr = bh[j], hz = bh[32 + j], hn = bh[64 + j];
            for (int k = 0; k < GRU_H; ++k) {
                float hv = h[k];
                hr += hv * Wh[k * 96 + j];
                hz += hv * Wh[k * 96 + 32 + j];
                hn += hv * Wh[k * 96 + 64 + j];
            }
            float xr = s_gx[b][dir][t5][j], xz = s_gx[b][dir][t5][32 + j];
            float xn = s_gx[b][dir][t5][64 + j];
            float r = 1.f / (1.f + __expf(-(xr + hr)));
            float z = 1.f / (1.f + __expf(-(xz + hz)));
            float nn = tanhf(xn + r * hn);
            float hnew = (1.f - z) * nn + z * h[j];
            __syncthreads();
            s_hh[b][dir][j] = hnew;
            __syncthreads();
        }
        s_jt[GAT_TOT + dir * GRU_H + j][b] = s_hh[b][dir][j];
    }
    __syncthreads();

    // MLP1: thread (hd, j1) computes 4 b's
    const int hd = tid >> 7, j1 = tid & 127;
    float v10, v11, v12, v13;
    {
        const float* W1 = hd ? vW1 : pW1;
        const float bb = (hd ? vb1 : pb1)[j1];
        v10 = v11 = v12 = v13 = bb;
        for (int c = 0; c < 320; ++c) {
            float w = W1[c * 128 + j1];
            float4 jt4 = *(const float4*)s_jt[c];
            v10 = fmaf(jt4.x, w, v10); v11 = fmaf(jt4.y, w, v11);
            v12 = fmaf(jt4.z, w, v12); v13 = fmaf(jt4.w, w, v13);
        }
    }
    {
        float q0 = v10, q1 = v11, q2 = v12, q3 = v13;
        float s0 = v10 * v10, s1 = v11 * v11, s2 = v12 * v12, s3 = v13 * v13;
        #pragma unroll
        for (int m = 1; m < 64; m <<= 1) {
            q0 += __shfl_xor(q0, m); q1 += __shfl_xor(q1, m);
            q2 += __shfl_xor(q2, m); q3 += __shfl_xor(q3, m);
            s0 += __shfl_xor(s0, m); s1 += __shfl_xor(s1, m);
            s2 += __shfl_xor(s2, m); s3 += __shfl_xor(s3, m);
        }
        if ((tid & 63) == 0) {
            const int wh = (tid >> 6) & 1;
            s_red[hd][wh][0][0] = q0; s_red[hd][wh][0][1] = s0;
            s_red[hd][wh][1][0] = q1; s_red[hd][wh][1][1] = s1;
            s_red[hd][wh][2][0] = q2; s_red[hd][wh][2][1] = s2;
            s_red[hd][wh][3][0] = q3; s_red[hd][wh][3][1] = s3;
        }
    }
    __syncthreads();
    {
        const float g = (hd ? vg1 : pg1)[j1], bt = (hd ? vbt1 : pbt1)[j1];
        float out[4];
        float vv[4] = {v10, v11, v12, v13};
        #pragma unroll
        for (int b = 0; b < BT; ++b) {
            float sum1 = s_red[hd][0][b][0] + s_red[hd][1][b][0];
            float sum2 = s_red[hd][0][b][1] + s_red[hd][1][b][1];
            float mean = sum1 * (1.f / 128.f);
            float var = sum2 * (1.f / 128.f) - mean * mean;
            out[b] = fmaxf((vv[b] - mean) * rsqrtf(var + 1e-5f) * g + bt, 0.f);
        }
        *(float4*)s_h1[hd][j1] = make_float4(out[0], out[1], out[2], out[3]);
    }
    __syncthreads();

    // MLP2: thread (hd2, half, j2), split-K 2
    float v20, v21, v22, v23;
    const int hd2 = tid >> 7, half = (tid >> 6) & 1, j2 = tid & 63;
    {
        const float* W2 = hd2 ? vW2 : pW2;
        const float bb2 = half ? 0.f : (hd2 ? vb2 : pb2)[j2];
        v20 = v21 = v22 = v23 = bb2;
        for (int c = half * 64; c < half * 64 + 64; ++c) {
            float w = W2[c * 64 + j2];
            float4 h14 = *(const float4*)s_h1[hd2][c];
            v20 = fmaf(h14.x, w, v20); v21 = fmaf(h14.y, w, v21);
            v22 = fmaf(h14.z, w, v22); v23 = fmaf(h14.w, w, v23);
        }
        if (half) *(float4*)s_p2b[hd2][j2] = make_float4(v20, v21, v22, v23);
    }
    __syncthreads();
    if (half == 0) {
        float4 pb4 = *(const float4*)s_p2b[hd2][j2];
        v20 += pb4.x; v21 += pb4.y; v22 += pb4.z; v23 += pb4.w;
        float q0 = v20, q1 = v21, q2 = v22, q3 = v23;
        float s0 = v20 * v20, s1 = v21 * v21, s2 = v22 * v22, s3 = v23 * v23;
        #pragma unroll
        for (int m = 1; m < 64; m <<= 1) {
            q0 += __shfl_xor(q0, m); q1 += __shfl_xor(q1, m);
            q2 += __shfl_xor(q2, m); q3 += __shfl_xor(q3, m);
            s0 += __shfl_xor(s0, m); s1 += __shfl_xor(s1, m);
            s2 += __shfl_xor(s2, m); s3 += __shfl_xor(s3, m);
        }
        const float g = (hd2 ? vg2 : pg2)[j2], bt = (hd2 ? vbt2 : pbt2)[j2];
        float sums1[4] = {q0, q1, q2, q3};
        float sums2[4] = {s0, s1, s2, s3};
        float vv[4] = {v20, v21, v22, v23};
        float out[4];
        #pragma unroll
        for (int b = 0; b < BT; ++b) {
            float mean = sums1[b] * (1.f / 64.f);
            float var = sums2[b] * (1.f / 64.f) - mean * mean;
            out[b] = fmaxf((vv[b] - mean) * rsqrtf(var + 1e-5f) * g + bt, 0.f);
        }
        *(float4*)s_h2[hd2][j2] = make_float4(out[0], out[1], out[2], out[3]);
    }
    __syncthreads();

    // outputs
    if (tid < 32) {
        const int b = tid >> 3, o = tid & 7;
        float v = pbo[o];
        for (int c = 0; c < 64; ++c) v += s_h2[0][c][b] * pWo[c * 8 + o];
        dout[(size_t)(b0 + b) * 8 + o] = v;
    } else if (tid < 36) {
        const int b = tid - 32;
        float v = vbo[0];
        for (int c = 0; c < 64; ++c) v += s_h2[1][c][b] * vWo[c];
        dout[(size_t)BB * 8 + b0 + b] = v;
    }
}

extern "C" void kernel_launch(void* const* d_in, const int* in_sizes, int n_in,
                              void* d_out, int out_size, void* d_ws, size_t ws_size,
                              hipStream_t stream) {
    (void)in_sizes; (void)n_in; (void)out_size; (void)ws_size;
    const float* selfF  = (const float*)d_in[0];
    const float* nbF    = (const float*)d_in[1];
    const float* mask   = (const float*)d_in[2];
    const float* projW  = (const float*)d_in[3];
    const float* projB  = (const float*)d_in[4];
    const float* projG  = (const float*)d_in[5];
    const float* projBt = (const float*)d_in[6];
    const float* coopW  = (const float*)d_in[7];
    const float* coopS  = (const float*)d_in[8];
    const float* coopD  = (const float*)d_in[9];
    const float* confW  = (const float*)d_in[10];
    const float* confS  = (const float*)d_in[11];
    const float* confD  = (const float*)d_in[12];
    const float* sageW  = (const float*)d_in[13];
    const float* sageB  = (const float*)d_in[14];
    const float* gfWx = (const float*)d_in[15];
    const float* gfWh = (const float*)d_in[16];
    const float* gfbx = (const float*)d_in[17];
    const float* gfbh = (const float*)d_in[18];
    const float* gbWx = (const float*)d_in[19];
    const float* gbWh = (const float*)d_in[20];
    const float* gbbx = (const float*)d_in[21];
    const float* gbbh = (const float*)d_in[22];
    const float* pW1  = (const float*)d_in[23];
    const float* pb1  = (const float*)d_in[24];
    const float* pg1  = (const float*)d_in[25];
    const float* pbt1 = (const float*)d_in[26];
    const float* pW2  = (const float*)d_in[27];
    const float* pb2  = (const float*)d_in[28];
    const float* pg2  = (const float*)d_in[29];
    const float* pbt2 = (const float*)d_in[30];
    const float* pWo  = (const float*)d_in[31];
    const float* pbo  = (const float*)d_in[32];
    const float* vW1  = (const float*)d_in[33];
    const float* vb1  = (const float*)d_in[34];
    const float* vg1  = (const float*)d_in[35];
    const float* vbt1 = (const float*)d_in[36];
    const float* vW2  = (const float*)d_in[37];
    const float* vb2  = (const float*)d_in[38];
    const float* vg2  = (const float*)d_in[39];
    const float* vbt2 = (const float*)d_in[40];
    const float* vWo  = (const float*)d_in[41];
    const float* vbo  = (const float*)d_in[42];

    float* hsage   = (float*)d_ws;                                    // B*T*64 f32
    float* embLast = hsage + (size_t)BB * TT * SAGE_H;                // B*256 f32
    unsigned short* wt = (unsigned short*)(embLast + (size_t)BB * GAT_TOT); // [256][64] bf16
    float* statc = (float*)(wt + 256 * GH);                           // [20] f32

    setup_kernel<<<2, 256, 0, stream>>>(coopW, confW, projW, projB, wt, statc);

    gat_sage_kernel<<<BB * TT, 256, 0, stream>>>(
        selfF, nbF, mask, projW, projB, projG, projBt,
        coopS, coopD, confS, confD, wt, statc,
        sageW, sageB, hsage, embLast);

    gru_head_kernel<<<BB / BT, 256, 0, stream>>>(
        hsage, embLast,
        gfWx, gfWh, gfbx, gfbh, gbWx, gbWh, gbbx, gbbh,
        pW1, pb1, pg1, pbt1, pW2, pb2, pg2, pbt2, pWo, pbo,
        vW1, vb1, vg1, vbt1, vW2, vb2, vg2, vbt2, vWo, vbo,
        (float*)d_out);
}

// Round 14
// 449.588 us; speedup vs baseline: 2.2125x; 1.1905x over previous
//
#include <hip/hip_runtime.h>
#include <hip/hip_bf16.h>
#include <math.h>

#define BB 4096
#define TT 5
#define KK 4
#define NLANES 12
#define GH 64
#define GO 32
#define GAT_TOT 256
#define SAGE_H 64
#define GRU_H 32
#define BT 4

typedef __attribute__((ext_vector_type(8))) short short8v;
typedef __attribute__((ext_vector_type(8))) unsigned short ushort8v;
typedef __attribute__((ext_vector_type(4))) unsigned short ushort4v;
typedef __attribute__((ext_vector_type(4))) float f32x4;

__device__ __forceinline__ unsigned short f2bf(float x) {
    __hip_bfloat16 h = __float2bfloat16(x);
    return __builtin_bit_cast(unsigned short, h);
}
__device__ __forceinline__ float bf2f(unsigned short b) {
    return __uint_as_float(((unsigned)b) << 16);
}

// VALU-pipe row reduce via DPP row_shl: lane i accumulates lanes >= i within
// its 16-lane row; lane (l15==0) ends with the full row sum.
// ctrl 0x101..0x10F = row_shl:1..15 (lane i reads lane i+N; OOB -> 0).
template <int CTRL>
__device__ __forceinline__ float dpp_radd(float v) {
    int t = __builtin_amdgcn_update_dpp(0, __builtin_bit_cast(int, v),
                                        CTRL, 0xf, 0xf, true);
    return v + __builtin_bit_cast(float, t);
}
__device__ __forceinline__ float row_sum16(float v) {
    v = dpp_radd<0x101>(v);   // row_shl:1
    v = dpp_radd<0x102>(v);   // row_shl:2
    v = dpp_radd<0x104>(v);   // row_shl:4
    v = dpp_radd<0x108>(v);   // row_shl:8
    return v;
}

// ---------------------------------------------------------------------------
// Setup (2 blocks): block 0 -> wt bf16 [256][64]; block 1 -> statc[20].
// ---------------------------------------------------------------------------
__global__ void setup_kernel(const float* __restrict__ coopW,
                             const float* __restrict__ confW,
                             const float* __restrict__ projW,
                             const float* __restrict__ projB,
                             unsigned short* __restrict__ wt,
                             float* __restrict__ statc) {
    const int tnum = threadIdx.x;
    if (blockIdx.x == 0) {
        int c = tnum;
        int g = c >> 7, hh = (c >> 5) & 3, o = c & 31;
        const float* W = (g ? confW : coopW) + hh * (GH * GO) + o;
        for (int k = 0; k < GH; ++k)
            wt[c * GH + k] = f2bf(W[k * GO]);
    } else if (tnum < 20) {
        float Wm[4], bm = 0.f;
        #pragma unroll
        for (int c = 0; c < 4; ++c) {
            float s = 0.f;
            for (int f = 0; f < GH; ++f) s += projW[c * GH + f];
            Wm[c] = s * (1.f / GH);
        }
        for (int f = 0; f < GH; ++f) bm += projB[f];
        bm *= (1.f / GH);

        float val;
        if (tnum < 10) {
            const int cs[10] = {0,0,0,0,1,1,1,2,2,3};
            const int ds[10] = {0,1,2,3,1,2,3,2,3,3};
            int c = cs[tnum], d = ds[tnum];
            float s = 0.f;
            for (int f = 0; f < GH; ++f)
                s += (projW[c * GH + f] - Wm[c]) * (projW[d * GH + f] - Wm[d]);
            val = s * (1.f / GH) * (c == d ? 1.f : 2.f);
        } else if (tnum < 14) {
            int c = tnum - 10;
            float s = 0.f;
            for (int f = 0; f < GH; ++f)
                s += (projW[c * GH + f] - Wm[c]) * (projB[f] - bm);
            val = s * (2.f / GH);
        } else if (tnum == 14) {
            float s = 0.f;
            for (int f = 0; f < GH; ++f)
                s += (projB[f] - bm) * (projB[f] - bm);
            val = s * (1.f / GH);
        } else if (tnum < 19) {
            val = Wm[tnum - 15];
        } else {
            val = bm;
        }
        statc[tnum] = val;
    }
}

// ---------------------------------------------------------------------------
// Kernel A: r12 + DPP reduce (DS->VALU, row_shl fixed), float4 softmax/proj
// reads, coop-specialized softmax.
// ---------------------------------------------------------------------------
__global__ __launch_bounds__(256, 4) void gat_sage_kernel(
    const float* __restrict__ selfF, const float* __restrict__ nbF,
    const float* __restrict__ mask,
    const float* __restrict__ projW, const float* __restrict__ projB,
    const float* __restrict__ projG, const float* __restrict__ projBt,
    const float* __restrict__ coopSrc, const float* __restrict__ coopDst,
    const float* __restrict__ confSrc, const float* __restrict__ confDst,
    const unsigned short* __restrict__ wt, const float* __restrict__ statc,
    const float* __restrict__ sageW, const float* __restrict__ sageB,
    float* __restrict__ hsage, float* __restrict__ embLast)
{
    __shared__ __align__(16) char s_all[40960];

    float* s_x = (float*)s_all;
    float2* s_stat = (float2*)(s_all + 1024);
    unsigned short* WhT = (unsigned short*)s_all;
    float (*s_att)[8][NLANES][16] = (float (*)[8][NLANES][16])s_all;
    float* s_in = (float*)s_all;
    float (*s_part)[SAGE_H] = (float (*)[SAGE_H])(s_all + 2048);   // [16][64]
    unsigned short* s_hb = (unsigned short*)(s_all + 32768);
    float (*s_sd)[8][64] = (float (*)[8][64])(s_all + 32768);

    const int bid = blockIdx.x;          // b*T + t
    const int b = bid / TT, t = bid % TT;
    const int tid = threadIdx.x;

    const int gh = tid >> 5;
    const int wv = tid >> 6, f = tid & 63;
    const int l15 = f & 15, g4 = f >> 4;

    if (tid < 60) {
        int inst = tid / 12, j = tid % 12;
        const float* xp = (inst == 0)
            ? (selfF + (size_t)bid * 48)
            : (nbF + (size_t)((b * KK + (inst - 1)) * TT + t) * 48);
        float4 xv = ((const float4*)xp)[j];
        ((float4*)s_x)[tid] = xv;
        const float* sc = statc;
        float mean = xv.x * sc[15] + xv.y * sc[16] + xv.z * sc[17] + xv.w * sc[18] + sc[19];
        float var = sc[0] * xv.x * xv.x + sc[1] * xv.x * xv.y + sc[2] * xv.x * xv.z
                  + sc[3] * xv.x * xv.w + sc[4] * xv.y * xv.y + sc[5] * xv.y * xv.z
                  + sc[6] * xv.y * xv.w + sc[7] * xv.z * xv.z + sc[8] * xv.z * xv.w
                  + sc[9] * xv.w * xv.w
                  + sc[10] * xv.x + sc[11] * xv.y + sc[12] * xv.z + sc[13] * xv.w + sc[14];
        s_stat[tid] = make_float2(mean, rsqrtf(fmaxf(var, 0.f) + 1e-5f));
    }

    const float pw0 = projW[0 * GH + f], pw1 = projW[1 * GH + f];
    const float pw2 = projW[2 * GH + f], pw3 = projW[3 * GH + f];
    const float pb = projB[f], pg = projG[f], pbt = projBt[f];
    __syncthreads();

    #pragma unroll
    for (int i = 0; i < 15; ++i) {
        const int r = wv + i * 4;
        float2 st = s_stat[r];
        float4 xr = ((const float4*)s_x)[r];
        float h = fmaf(xr.x, pw0, fmaf(xr.y, pw1,
                  fmaf(xr.z, pw2, fmaf(xr.w, pw3, pb))));
        float nv = (h - st.x) * (st.y * pg) + pbt;
        nv = fmaxf(nv, 0.f);
        s_hb[r * 64 + (((f >> 3) ^ (r & 7)) << 3) + (f & 7)] = f2bf(nv);
    }
    {
        const int r = 60 + wv;
        s_hb[r * 64 + (((f >> 3) ^ (r & 7)) << 3) + (f & 7)] = 0;
    }
    __syncthreads();

    {
        f32x4 c[4][4];
        #pragma unroll
        for (int mt = 0; mt < 4; ++mt)
            #pragma unroll
            for (int nt = 0; nt < 4; ++nt)
                c[mt][nt] = (f32x4){0.f, 0.f, 0.f, 0.f};

        #pragma unroll
        for (int kt = 0; kt < 2; ++kt) {
            const int kc = kt * 4 + g4;
            short8v a[4], bfr[4];
            #pragma unroll
            for (int mt = 0; mt < 4; ++mt) {
                const int r = mt * 16 + l15;
                a[mt] = *(const short8v*)&s_hb[r * 64 + ((kc ^ (r & 7)) << 3)];
            }
            #pragma unroll
            for (int nt = 0; nt < 4; ++nt)
                bfr[nt] = *(const short8v*)&wt[(wv * 64 + nt * 16 + l15) * GH + kc * 8];
            #pragma unroll
            for (int mt = 0; mt < 4; ++mt)
                #pragma unroll
                for (int nt = 0; nt < 4; ++nt)
                    c[mt][nt] = __builtin_amdgcn_mfma_f32_16x16x32_bf16(
                        a[mt], bfr[nt], c[mt][nt], 0, 0, 0);
        }

        __syncthreads();   // s_hb reads done -> s_sd alias safe

        // attention scalars from C-frags: DPP row-sum (VALU pipe, no DS)
        {
            float asv[4], adv[4];
            #pragma unroll
            for (int nt = 0; nt < 4; ++nt) {
                const int cc = wv * 64 + nt * 16 + l15;
                const int g = cc >> 7, hh = (cc >> 5) & 3, oo = cc & 31;
                asv[nt] = (g ? confSrc : coopSrc)[hh * GO + oo];
                adv[nt] = (g ? confDst : coopDst)[hh * GO + oo];
            }
            #pragma unroll
            for (int p = 0; p < 2; ++p) {
                const int ghw = 2 * wv + p;
                #pragma unroll
                for (int mt = 0; mt < 4; ++mt) {
                    float sv[4], dv[4];
                    #pragma unroll
                    for (int r = 0; r < 4; ++r) {
                        sv[r] = row_sum16(c[mt][2 * p][r] * asv[2 * p]
                                        + c[mt][2 * p + 1][r] * asv[2 * p + 1]);
                        dv[r] = row_sum16(c[mt][2 * p][r] * adv[2 * p]
                                        + c[mt][2 * p + 1][r] * adv[2 * p + 1]);
                    }
                    if (l15 == 0) {
                        const int rb = mt * 16 + g4 * 4;
                        *(float4*)&s_sd[0][ghw][rb] = make_float4(sv[0], sv[1], sv[2], sv[3]);
                        *(float4*)&s_sd[1][ghw][rb] = make_float4(dv[0], dv[1], dv[2], dv[3]);
                    }
                }
            }
        }

        #pragma unroll
        for (int mt = 0; mt < 4; ++mt) {
            #pragma unroll
            for (int nt = 0; nt < 4; ++nt) {
                const int cc = wv * 64 + nt * 16 + l15;
                const int rb = mt * 16 + g4 * 4;
                ushort4v p;
                p.x = f2bf(c[mt][nt][0]); p.y = f2bf(c[mt][nt][1]);
                p.z = f2bf(c[mt][nt][2]); p.w = f2bf(c[mt][nt][3]);
                const int idx = cc * 64 + (((rb >> 3) ^ (cc & 7)) << 3) + (rb & 7);
                *(ushort4v*)&WhT[idx] = p;
            }
        }
    }
    __syncthreads();

    float acc[60];
    {
        const int cs = tid & 7;
        #pragma unroll
        for (int ch = 0; ch < 8; ++ch) {
            ushort8v v = *(const ushort8v*)&WhT[tid * 64 + ((ch ^ cs) << 3)];
            #pragma unroll
            for (int j = 0; j < 8; ++j) {
                const int r = ch * 8 + j;
                if (r < 60) acc[r] = bf2f(v[j]);
            }
        }
    }
    __syncthreads();

    // ---- parallel masked softmax: coop 3-exp path / conf 12 with f4 reads --
    #pragma unroll
    for (int round = 0; round < 2; ++round) {
        const int task = tid + round * 256;
        if (task < 480) {
            const int inst = task / 96;
            const int rem = task - inst * 96;
            const int gh2 = rem / 12, n2 = rem - (rem / 12) * 12;
            const int an = n2 / 3;
            const float sn = s_sd[0][gh2][inst * 12 + n2];
            const int sw = n2 & 3;
            float* arow = s_att[inst][gh2][n2];
            if (gh2 < 4) {
                // coop: only m in {3an,3an+1,3an+2} valid; others never read
                const int base = 3 * an;
                const float* dvp = &s_sd[1][gh2][inst * 12 + base];
                float e0 = sn + dvp[0], e1 = sn + dvp[1], e2 = sn + dvp[2];
                e0 = e0 > 0.f ? e0 : 0.2f * e0;
                e1 = e1 > 0.f ? e1 : 0.2f * e1;
                e2 = e2 > 0.f ? e2 : 0.2f * e2;
                float mx = fmaxf(fmaxf(e0, e1), e2);
                e0 = __expf(e0 - mx); e1 = __expf(e1 - mx); e2 = __expf(e2 - mx);
                const float inv = 1.f / (e0 + e1 + e2);
                const float ee[3] = {e0 * inv, e1 * inv, e2 * inv};
                #pragma unroll
                for (int i = 0; i < 3; ++i) {
                    const int m = base + i;
                    arow[(((m >> 2) ^ sw) << 2) | (m & 3)] = ee[i];
                }
            } else {
                const float4* dvp = (const float4*)&s_sd[1][gh2][inst * 12];
                float4 d0 = dvp[0], d1 = dvp[1], d2 = dvp[2];
                const float dva[12] = {d0.x, d0.y, d0.z, d0.w,
                                       d1.x, d1.y, d1.z, d1.w,
                                       d2.x, d2.y, d2.z, d2.w};
                float vq[12];
                float mx = -1e30f;
                #pragma unroll
                for (int mm = 0; mm < NLANES; ++mm) {
                    bool valid = (mm / 3 != an) || (mm == n2);
                    float ev = sn + dva[mm];
                    ev = ev > 0.f ? ev : 0.2f * ev;
                    vq[mm] = valid ? ev : -1e30f;
                    mx = fmaxf(mx, vq[mm]);
                }
                float sum = 0.f;
                #pragma unroll
                for (int mm = 0; mm < NLANES; ++mm) {
                    float ex = __expf(vq[mm] - mx);
                    vq[mm] = ex; sum += ex;
                }
                const float inv = 1.f / sum;
                float4* arow4 = (float4*)arow;
                arow4[0 ^ sw] = make_float4(vq[0] * inv, vq[1] * inv, vq[2] * inv, vq[3] * inv);
                arow4[1 ^ sw] = make_float4(vq[4] * inv, vq[5] * inv, vq[6] * inv, vq[7] * inv);
                arow4[2 ^ sw] = make_float4(vq[8] * inv, vq[9] * inv, vq[10] * inv, vq[11] * inv);
            }
        }
    }
    __syncthreads();

    // ---- pool: sparsity-specialized (coop 3-term, conf 10-term) ----
    {
        float pooled_arr[5];
        if (wv < 2) {
            #pragma unroll
            for (int inst = 0; inst < 5; ++inst) {
                float pooled = 0.f;
                #pragma unroll
                for (int n = 0; n < NLANES; ++n) {
                    const int an = n / 3;
                    const int sw = n & 3;
                    const float4* arow = (const float4*)s_att[inst][gh][n];
                    float v;
                    if (an == 0) {
                        float4 a0 = arow[0 ^ sw];
                        v = a0.x * acc[inst * 12 + 0] + a0.y * acc[inst * 12 + 1]
                          + a0.z * acc[inst * 12 + 2];
                    } else if (an == 1) {
                        float4 a0 = arow[0 ^ sw], a1 = arow[1 ^ sw];
                        v = a0.w * acc[inst * 12 + 3] + a1.x * acc[inst * 12 + 4]
                          + a1.y * acc[inst * 12 + 5];
                    } else if (an == 2) {
                        float4 a1 = arow[1 ^ sw], a2 = arow[2 ^ sw];
                        v = a1.z * acc[inst * 12 + 6] + a1.w * acc[inst * 12 + 7]
                          + a2.x * acc[inst * 12 + 8];
                    } else {
                        float4 a2 = arow[2 ^ sw];
                        v = a2.y * acc[inst * 12 + 9] + a2.z * acc[inst * 12 + 10]
                          + a2.w * acc[inst * 12 + 11];
                    }
                    v = v > 0.f ? v : (__expf(v) - 1.f);
                    pooled += v;
                }
                pooled_arr[inst] = pooled * (1.f / 12.f);
            }
        } else {
            #pragma unroll
            for (int inst = 0; inst < 5; ++inst) {
                float pooled = 0.f;
                #pragma unroll
                for (int n = 0; n < NLANES; ++n) {
                    const int sw = n & 3;
                    const float4* arow = (const float4*)s_att[inst][gh][n];
                    float4 q0 = arow[0 ^ sw], q1 = arow[1 ^ sw], q2 = arow[2 ^ sw];
                    const float av[12] = {q0.x, q0.y, q0.z, q0.w,
                                          q1.x, q1.y, q1.z, q1.w,
                                          q2.x, q2.y, q2.z, q2.w};
                    float v = 0.f;
                    #pragma unroll
                    for (int m = 0; m < 12; ++m) {
                        if (m / 3 == n / 3 && m != n) continue;
                        v += av[m] * acc[inst * 12 + m];
                    }
                    v = v > 0.f ? v : (__expf(v) - 1.f);
                    pooled += v;
                }
                pooled_arr[inst] = pooled * (1.f / 12.f);
            }
        }
        __syncthreads();   // att dead

        const float m0 = mask[b * KK + 0], m1 = mask[b * KK + 1];
        const float m2 = mask[b * KK + 2], m3 = mask[b * KK + 3];
        const float inv = 1.f / fmaxf(m0 + m1 + m2 + m3, 1.f);
        s_in[tid] = pooled_arr[0];
        s_in[GAT_TOT + tid] = (m0 * pooled_arr[1] + m1 * pooled_arr[2]
                             + m2 * pooled_arr[3] + m3 * pooled_arr[4]) * inv;
        if (t == TT - 1) embLast[(size_t)b * GAT_TOT + tid] = pooled_arr[0];
    }
    __syncthreads();

    // ---- sage: thread=(q,j4), dwordx4 weight loads, 16-way split-K ----
    {
        const int q = tid >> 4, j4 = (tid & 15) << 2;
        const float4* si4 = (const float4*)s_in;
        float v0 = 0.f, v1 = 0.f, v2 = 0.f, v3 = 0.f;
        #pragma unroll 4
        for (int c4 = q * 8; c4 < q * 8 + 8; ++c4) {
            float4 s4 = si4[c4];
            const float* Wp = sageW + (c4 * 4) * SAGE_H + j4;
            float4 w;
            w = *(const float4*)(Wp);
            v0 = fmaf(s4.x, w.x, v0); v1 = fmaf(s4.x, w.y, v1);
            v2 = fmaf(s4.x, w.z, v2); v3 = fmaf(s4.x, w.w, v3);
            w = *(const float4*)(Wp + SAGE_H);
            v0 = fmaf(s4.y, w.x, v0); v1 = fmaf(s4.y, w.y, v1);
            v2 = fmaf(s4.y, w.z, v2); v3 = fmaf(s4.y, w.w, v3);
            w = *(const float4*)(Wp + 2 * SAGE_H);
            v0 = fmaf(s4.z, w.x, v0); v1 = fmaf(s4.z, w.y, v1);
            v2 = fmaf(s4.z, w.z, v2); v3 = fmaf(s4.z, w.w, v3);
            w = *(const float4*)(Wp + 3 * SAGE_H);
            v0 = fmaf(s4.w, w.x, v0); v1 = fmaf(s4.w, w.y, v1);
            v2 = fmaf(s4.w, w.z, v2); v3 = fmaf(s4.w, w.w, v3);
        }
        *(float4*)&s_part[q][j4] = make_float4(v0, v1, v2, v3);
    }
    __syncthreads();
    if (tid < SAGE_H) {
        float v = sageB[tid];
        #pragma unroll
        for (int q = 0; q < 16; ++q) v += s_part[q][tid];
        hsage[(size_t)bid * SAGE_H + tid] = fmaxf(v, 0.f);
    }
}

// ---------------------------------------------------------------------------
// Kernel B: BATCH=4 (unchanged from r12).
// ---------------------------------------------------------------------------
__global__ __launch_bounds__(256) void gru_head_kernel(
    const float* __restrict__ hsage, const float* __restrict__ embLast,
    const float* __restrict__ gfWx, const float* __restrict__ gfWh,
    const float* __restrict__ gfbx, const float* __restrict__ gfbh,
    const float* __restrict__ gbWx, const float* __restrict__ gbWh,
    const float* __restrict__ gbbx, const float* __restrict__ gbbh,
    const float* __restrict__ pW1, const float* __restrict__ pb1,
    const float* __restrict__ pg1, const float* __restrict__ pbt1,
    const float* __restrict__ pW2, const float* __restrict__ pb2,
    const float* __restrict__ pg2, const float* __restrict__ pbt2,
    const float* __restrict__ pWo, const float* __restrict__ pbo,
    const float* __restrict__ vW1, const float* __restrict__ vb1,
    const float* __restrict__ vg1, const float* __restrict__ vbt1,
    const float* __restrict__ vW2, const float* __restrict__ vb2,
    const float* __restrict__ vg2, const float* __restrict__ vbt2,
    const float* __restrict__ vWo, const float* __restrict__ vbo,
    float* __restrict__ dout)
{
    __shared__ __align__(16) float s_seq[BT][TT * SAGE_H];
    __shared__ float s_gx[BT][2][TT][96];
    __shared__ float s_hh[BT][2][GRU_H];
    __shared__ __align__(16) float s_jt[320][BT];
    __shared__ __align__(16) float s_h1[2][128][BT];
    __shared__ __align__(16) float s_p2b[2][64][BT];
    __shared__ __align__(16) float s_h2[2][64][BT];
    __shared__ float s_red[2][2][BT][2];

    const int b0 = blockIdx.x * BT;
    const int tid = threadIdx.x;

    for (int i = tid; i < BT * 80; i += 256) {
        int b = i / 80, qq = i - (i / 80) * 80;
        ((float4*)s_seq[b])[qq] =
            ((const float4*)(hsage + (size_t)(b0 + b) * (TT * SAGE_H)))[qq];
    }
    for (int i = tid; i < BT * 256; i += 256) {
        int b = i >> 8, c = i & 255;
        s_jt[c][b] = embLast[(size_t)(b0 + b) * GAT_TOT + c];
    }
    if (tid < BT * 64) s_hh[tid >> 6][(tid >> 5) & 1][tid & 31] = 0.f;
    __syncthreads();

    for (int task = tid; task < BT * 960; task += 256) {
        const int b = task / 960, rem = task - b * 960;
        const int dir = rem >= 480, rem2 = rem - dir * 480;
        const int t5 = rem2 / 96, j = rem2 - t5 * 96;
        const float* Wx = dir ? gbWx : gfWx;
        const float* x = s_seq[b] + t5 * SAGE_H;
        float v = (dir ? gbbx : gfbx)[j];
        for (int f2 = 0; f2 < SAGE_H; ++f2) v += x[f2] * Wx[f2 * 96 + j];
        s_gx[b][dir][t5][j] = v;
    }
    __syncthreads();

    {
        const int b = tid >> 6, dir = (tid >> 5) & 1, j = tid & 31;
        const float* Wh = dir ? gbWh : gfWh;
        const float* bh = dir ? gbbh : gfbh;
        for (int s = 0; s < TT; ++s) {
            const int t5 = dir ? (TT - 1 - s) : s;
            const float* h = s_hh[b][dir];
            float hr = bh[j], hz = bh[32 + j], hn = bh[64 + j];
            for (int k = 0; k < GRU_H; ++k) {
                float hv = h[k];
                hr += hv * Wh[k * 96 + j];
                hz += hv * Wh[k * 96 + 32 + j];
                hn += hv * Wh[k * 96 + 64 + j];
            }
            float xr = s_gx[b][dir][t5][j], xz = s_gx[b][dir][t5][32 + j];
            float xn = s_gx[b][dir][t5][64 + j];
            float r = 1.f / (1.f + __expf(-(xr + hr)));
            float z = 1.f / (1.f + __expf(-(xz + hz)));
            float nn = tanhf(xn + r * hn);
            float hnew = (1.f - z) * nn + z * h[j];
            __syncthreads();
            s_hh[b][dir][j] = hnew;
            __syncthreads();
        }
        s_jt[GAT_TOT + dir * GRU_H + j][b] = s_hh[b][dir][j];
    }
    __syncthreads();

    const int hd = tid >> 7, j1 = tid & 127;
    float v10, v11, v12, v13;
    {
        const float* W1 = hd ? vW1 : pW1;
        const float bb = (hd ? vb1 : pb1)[j1];
        v10 = v11 = v12 = v13 = bb;
        for (int c = 0; c < 320; ++c) {
            float w = W1[c * 128 + j1];
            float4 jt4 = *(const float4*)s_jt[c];
            v10 = fmaf(jt4.x, w, v10); v11 = fmaf(jt4.y, w, v11);
            v12 = fmaf(jt4.z, w, v12); v13 = fmaf(jt4.w, w, v13);
        }
    }
    {
        float q0 = v10, q1 = v11, q2 = v12, q3 = v13;
        float s0 = v10 * v10, s1 = v11 * v11, s2 = v12 * v12, s3 = v13 * v13;
        #pragma unroll
        for (int m = 1; m < 64; m <<= 1) {
            q0 += __shfl_xor(q0, m); q1 += __shfl_xor(q1, m);
            q2 += __shfl_xor(q2, m); q3 += __shfl_xor(q3, m);
            s0 += __shfl_xor(s0, m); s1 += __shfl_xor(s1, m);
            s2 += __shfl_xor(s2, m); s3 += __shfl_xor(s3, m);
        }
        if ((tid & 63) == 0) {
            const int wh = (tid >> 6) & 1;
            s_red[hd][wh][0][0] = q0; s_red[hd][wh][0][1] = s0;
            s_red[hd][wh][1][0] = q1; s_red[hd][wh][1][1] = s1;
            s_red[hd][wh][2][0] = q2; s_red[hd][wh][2][1] = s2;
            s_red[hd][wh][3][0] = q3; s_red[hd][wh][3][1] = s3;
        }
    }
    __syncthreads();
    {
        const float g = (hd ? vg1 : pg1)[j1], bt = (hd ? vbt1 : pbt1)[j1];
        float out[4];
        float vv[4] = {v10, v11, v12, v13};
        #pragma unroll
        for (int b = 0; b < BT; ++b) {
            float sum1 = s_red[hd][0][b][0] + s_red[hd][1][b][0];
            float sum2 = s_red[hd][0][b][1] + s_red[hd][1][b][1];
            float mean = sum1 * (1.f / 128.f);
            float var = sum2 * (1.f / 128.f) - mean * mean;
            out[b] = fmaxf((vv[b] - mean) * rsqrtf(var + 1e-5f) * g + bt, 0.f);
        }
        *(float4*)s_h1[hd][j1] = make_float4(out[0], out[1], out[2], out[3]);
    }
    __syncthreads();

    float v20, v21, v22, v23;
    const int hd2 = tid >> 7, half = (tid >> 6) & 1, j2 = tid & 63;
    {
        const float* W2 = hd2 ? vW2 : pW2;
        const float bb2 = half ? 0.f : (hd2 ? vb2 : pb2)[j2];
        v20 = v21 = v22 = v23 = bb2;
        for (int c = half * 64; c < half * 64 + 64; ++c) {
            float w = W2[c * 64 + j2];
            float4 h14 = *(const float4*)s_h1[hd2][c];
            v20 = fmaf(h14.x, w, v20); v21 = fmaf(h14.y, w, v21);
            v22 = fmaf(h14.z, w, v22); v23 = fmaf(h14.w, w, v23);
        }
        if (half) *(float4*)s_p2b[hd2][j2] = make_float4(v20, v21, v22, v23);
    }
    __syncthreads();
    if (half == 0) {
        float4 pb4 = *(const float4*)s_p2b[hd2][j2];
        v20 += pb4.x; v21 += pb4.y; v22 += pb4.z; v23 += pb4.w;
        float q0 = v20, q1 = v21, q2 = v22, q3 = v23;
        float s0 = v20 * v20, s1 = v21 * v21, s2 = v22 * v22, s3 = v23 * v23;
        #pragma unroll
        for (int m = 1; m < 64; m <<= 1) {
            q0 += __shfl_xor(q0, m); q1 += __shfl_xor(q1, m);
            q2 += __shfl_xor(q2, m); q3 += __shfl_xor(q3, m);
            s0 += __shfl_xor(s0, m); s1 += __shfl_xor(s1, m);
            s2 += __shfl_xor(s2, m); s3 += __shfl_xor(s3, m);
        }
        const float g = (hd2 ? vg2 : pg2)[j2], bt = (hd2 ? vbt2 : pbt2)[j2];
        float sums1[4] = {q0, q1, q2, q3};
        float sums2[4] = {s0, s1, s2, s3};
        float vv[4] = {v20, v21, v22, v23};
        float out[4];
        #pragma unroll
        for (int b = 0; b < BT; ++b) {
            float mean = sums1[b] * (1.f / 64.f);
            float var = sums2[b] * (1.f / 64.f) - mean * mean;
            out[b] = fmaxf((vv[b] - mean) * rsqrtf(var + 1e-5f) * g + bt, 0.f);
        }
        *(float4*)s_h2[hd2][j2] = make_float4(out[0], out[1], out[2], out[3]);
    }
    __syncthreads();

    if (tid < 32) {
        const int b = tid >> 3, o = tid & 7;
        float v = pbo[o];
        for (int c = 0; c < 64; ++c) v += s_h2[0][c][b] * pWo[c * 8 + o];
        dout[(size_t)(b0 + b) * 8 + o] = v;
    } else if (tid < 36) {
        const int b = tid - 32;
        float v = vbo[0];
        for (int c = 0; c < 64; ++c) v += s_h2[1][c][b] * vWo[c];
        dout[(size_t)BB * 8 + b0 + b] = v;
    }
}

extern "C" void kernel_launch(void* const* d_in, const int* in_sizes, int n_in,
                              void* d_out, int out_size, void* d_ws, size_t ws_size,
                              hipStream_t stream) {
    (void)in_sizes; (void)n_in; (void)out_size; (void)ws_size;
    const float* selfF  = (const float*)d_in[0];
    const float* nbF    = (const float*)d_in[1];
    const float* mask   = (const float*)d_in[2];
    const float* projW  = (const float*)d_in[3];
    const float* projB  = (const float*)d_in[4];
    const float* projG  = (const float*)d_in[5];
    const float* projBt = (const float*)d_in[6];
    const float* coopW  = (const float*)d_in[7];
    const float* coopS  = (const float*)d_in[8];
    const float* coopD  = (const float*)d_in[9];
    const float* confW  = (const float*)d_in[10];
    const float* confS  = (const float*)d_in[11];
    const float* confD  = (const float*)d_in[12];
    const float* sageW  = (const float*)d_in[13];
    const float* sageB  = (const float*)d_in[14];
    const float* gfWx = (const float*)d_in[15];
    const float* gfWh = (const float*)d_in[16];
    const float* gfbx = (const float*)d_in[17];
    const float* gfbh = (const float*)d_in[18];
    const float* gbWx = (const float*)d_in[19];
    const float* gbWh = (const float*)d_in[20];
    const float* gbbx = (const float*)d_in[21];
    const float* gbbh = (const float*)d_in[22];
    const float* pW1  = (const float*)d_in[23];
    const float* pb1  = (const float*)d_in[24];
    const float* pg1  = (const float*)d_in[25];
    const float* pbt1 = (const float*)d_in[26];
    const float* pW2  = (const float*)d_in[27];
    const float* pb2  = (const float*)d_in[28];
    const float* pg2  = (const float*)d_in[29];
    const float* pbt2 = (const float*)d_in[30];
    const float* pWo  = (const float*)d_in[31];
    const float* pbo  = (const float*)d_in[32];
    const float* vW1  = (const float*)d_in[33];
    const float* vb1  = (const float*)d_in[34];
    const float* vg1  = (const float*)d_in[35];
    const float* vbt1 = (const float*)d_in[36];
    const float* vW2  = (const float*)d_in[37];
    const float* vb2  = (const float*)d_in[38];
    const float* vg2  = (const float*)d_in[39];
    const float* vbt2 = (const float*)d_in[40];
    const float* vWo  = (const float*)d_in[41];
    const float* vbo  = (const float*)d_in[42];

    float* hsage   = (float*)d_ws;
    float* embLast = hsage + (size_t)BB * TT * SAGE_H;
    unsigned short* wt = (unsigned short*)(embLast + (size_t)BB * GAT_TOT);
    float* statc = (float*)(wt + 256 * GH);

    setup_kernel<<<2, 256, 0, stream>>>(coopW, confW, projW, projB, wt, statc);

    gat_sage_kernel<<<BB * TT, 256, 0, stream>>>(
        selfF, nbF, mask, projW, projB, projG, projBt,
        coopS, coopD, confS, confD, wt, statc,
        sageW, sageB, hsage, embLast);

    gru_head_kernel<<<BB / BT, 256, 0, stream>>>(
        hsage, embLast,
        gfWx, gfWh, gfbx, gfbh, gbWx, gbWh, gbbx, gbbh,
        pW1, pb1, pg1, pbt1, pW2, pb2, pg2, pbt2, pWo, pbo,
        vW1, vb1, vg1, vbt1, vW2, vb2, vg2, vbt2, vWo, vbo,
        (float*)d_out);
}